// Round 1
// baseline (514.206 us; speedup 1.0000x reference)
//
#include <hip/hip_runtime.h>
#include <hip/hip_bf16.h>
#include <math.h>

#define BB   1
#define H    16
#define HKV  4
#define G    4      // H / HKV
#define NN   2048
#define D    64
#define HID  1024
#define CB   16
#define W    128    // NN / CB
#define NSEL 4
#define WIN  64
#define NEGV -1e10f
#define SCALE 0.125f   // D^-0.5

__device__ inline float wave_sum(float x) {
    for (int o = 32; o > 0; o >>= 1) x += __shfl_xor(x, o, 64);
    return x;
}
__device__ inline float wave_max(float x) {
    for (int o = 32; o > 0; o >>= 1) x = fmaxf(x, __shfl_xor(x, o, 64));
    return x;
}

// ---------------------------------------------------------------------------
// K1: compressed K/V rows: ckf/cvf[hkv][j][d], j=0 -> mem kv, j>=1 -> rmsnorm(mean block)
__global__ __launch_bounds__(64) void k_compress(
    const float* __restrict__ k, const float* __restrict__ v,
    const float* __restrict__ memkv,
    const float* __restrict__ ksc, const float* __restrict__ vsc,
    float* __restrict__ ckf, float* __restrict__ cvf)
{
    int bid = blockIdx.x;               // hk*(W+1)+j
    int hk = bid / (W + 1), j = bid % (W + 1);
    int d = threadIdx.x;
    float xk, xv;
    if (j == 0) {
        xk = memkv[(0 * HKV + hk) * D + d];
        xv = memkv[(1 * HKV + hk) * D + d];
    } else {
        int jb = j - 1;
        const float* kp = k + ((size_t)hk * NN + (size_t)jb * CB) * D + d;
        const float* vp = v + ((size_t)hk * NN + (size_t)jb * CB) * D + d;
        float sk = 0.f, sv = 0.f;
        for (int t = 0; t < CB; t++) { sk += kp[t * D]; sv += vp[t * D]; }
        xk = sk * (1.0f / CB);
        xv = sv * (1.0f / CB);
        float msk = wave_sum(xk * xk) * (1.0f / D);
        float msv = wave_sum(xv * xv) * (1.0f / D);
        xk = xk * rsqrtf(msk + 1e-6f) * ksc[d];
        xv = xv * rsqrtf(msv + 1e-6f) * vsc[d];
    }
    ckf[((size_t)hk * (W + 1) + j) * D + d] = xk;
    cvf[((size_t)hk * (W + 1) + j) * D + d] = xv;
}

// ---------------------------------------------------------------------------
// K2: compressed attention + importance mean over group + top-k selection.
// One block per (hk, i); 4 waves = 4 heads of the group.
__global__ __launch_bounds__(256) void k_cattn(
    const float* __restrict__ q,
    const float* __restrict__ ckf, const float* __restrict__ cvf,
    float* __restrict__ outc, int* __restrict__ selidx)
{
    int bid = blockIdx.x;               // hk*NN + i
    int hk = bid / NN, i = bid % NN;
    int wv = threadIdx.x >> 6;          // wave id == head-in-group
    int lane = threadIdx.x & 63;
    int h = hk * G + wv;

    __shared__ float qs[G][D];
    __shared__ float ssim[G][W + 4];
    __shared__ float sp[G][W + 4];
    __shared__ float simp[W];

    qs[wv][lane] = q[((size_t)h * NN + i) * D + lane];
    __syncthreads();

    // sims: lane handles j = lane, lane+64, (lane==0 -> 128)
    for (int jj = 0; jj < 3; jj++) {
        int j = lane + 64 * jj;
        if (j <= W) {
            const float* cr = ckf + ((size_t)hk * (W + 1) + j) * D;
            float s = 0.f;
            for (int d = 0; d < D; d++) s += qs[wv][d] * cr[d];
            s *= SCALE;
            if (j > 0 && !(j * CB - 1 < i)) s = NEGV;   // block j-1 causal mask
            ssim[wv][j] = s;
        }
    }
    __syncthreads();

    // importance mean over the 4 heads (wave 0), then top-k (lane 0)
    if (wv == 0) {
        for (int jj = 0; jj < 2; jj++) {
            int jb = lane + 64 * jj;
            simp[jb] = 0.25f * (ssim[0][jb + 1] + ssim[1][jb + 1] +
                                ssim[2][jb + 1] + ssim[3][jb + 1]);
        }
        if (lane == 0) {
            unsigned long long m0 = 0ull, m1 = 0ull;
            for (int s = 0; s < NSEL; s++) {
                float best = -INFINITY; int bi = 0;
                for (int jb = 0; jb < W; jb++) {
                    bool tk = (jb < 64) ? ((m0 >> jb) & 1ull) : ((m1 >> (jb - 64)) & 1ull);
                    float vv = simp[jb];
                    if (!tk && vv > best) { best = vv; bi = jb; }
                }
                if (bi < 64) m0 |= 1ull << bi; else m1 |= 1ull << (bi - 64);
                selidx[((size_t)hk * NN + i) * NSEL + s] = bi;
            }
        }
    }

    // per-head softmax over 129 entries
    float m = -INFINITY;
    for (int jj = 0; jj < 3; jj++) {
        int j = lane + 64 * jj;
        if (j <= W) m = fmaxf(m, ssim[wv][j]);
    }
    m = wave_max(m);
    float psum = 0.f;
    for (int jj = 0; jj < 3; jj++) {
        int j = lane + 64 * jj;
        if (j <= W) {
            float p = expf(ssim[wv][j] - m);
            sp[wv][j] = p;
            psum += p;
        }
    }
    psum = wave_sum(psum);
    __syncthreads();

    // out_c[d] for d = lane
    float acc = 0.f;
    for (int j = 0; j <= W; j++)
        acc += sp[wv][j] * cvf[((size_t)hk * (W + 1) + j) * D + lane];
    outc[((size_t)h * NN + i) * D + lane] = acc / psum;
}

// ---------------------------------------------------------------------------
// K3: selected-block attention. One wave per (h, i); 64 keys (4 blocks x 16).
__global__ __launch_bounds__(64) void k_selattn(
    const float* __restrict__ q,
    const float* __restrict__ k, const float* __restrict__ v,
    const int* __restrict__ selidx, float* __restrict__ outf)
{
    int bid = blockIdx.x;               // h*NN + i
    int h = bid / NN, i = bid % NN;
    int hk = h / G;
    int l = threadIdx.x;

    __shared__ float qs[D];
    __shared__ float ps[64];
    __shared__ int   pos_s[64];

    qs[l] = q[((size_t)h * NN + i) * D + l];
    int sb = selidx[((size_t)hk * NN + i) * NSEL + (l >> 4)];
    int pos = sb * CB + (l & 15);
    pos_s[l] = pos;
    __syncthreads();

    const float* kr = k + ((size_t)hk * NN + pos) * D;
    float s = 0.f;
    for (int d = 0; d < D; d++) s += qs[d] * kr[d];
    s *= SCALE;
    if (pos > i) s = NEGV;

    float m = wave_max(s);
    float p = expf(s - m);
    float psum = wave_sum(p);
    ps[l] = p;
    __syncthreads();

    float acc = 0.f;
    for (int j = 0; j < 64; j++)
        acc += ps[j] * v[((size_t)hk * NN + pos_s[j]) * D + l];
    outf[((size_t)h * NN + i) * D + l] = acc / psum;
}

// ---------------------------------------------------------------------------
// K4: sliding-window attention. One wave per (h, i); keys i-63..i.
__global__ __launch_bounds__(64) void k_swin(
    const float* __restrict__ q,
    const float* __restrict__ k, const float* __restrict__ v,
    float* __restrict__ outs)
{
    int bid = blockIdx.x;
    int h = bid / NN, i = bid % NN;
    int hk = h / G;
    int l = threadIdx.x;

    __shared__ float qs[D];
    __shared__ float ps[64];

    qs[l] = q[((size_t)h * NN + i) * D + l];
    __syncthreads();

    int pos = i - (WIN - 1) + l;
    int cpos = pos < 0 ? 0 : pos;
    const float* kr = k + ((size_t)hk * NN + cpos) * D;
    float s = 0.f;
    for (int d = 0; d < D; d++) s += qs[d] * kr[d];
    s *= SCALE;
    if (pos < 0) s = NEGV;

    float m = wave_max(s);
    float p = expf(s - m);     // exp(NEGV - m) == 0.0f exactly
    float psum = wave_sum(p);
    ps[l] = p;
    __syncthreads();

    int base = i - (WIN - 1);
    float acc = 0.f;
    for (int j = 0; j < 64; j++) {
        int pj = base + j;
        int cp = pj < 0 ? 0 : pj;
        acc += ps[j] * v[((size_t)hk * NN + cp) * D + l];
    }
    outs[((size_t)h * NN + i) * D + l] = acc / psum;
}

// ---------------------------------------------------------------------------
// K5: gates = sigmoid(hidden @ combiner_w^T + b). One block per token.
__global__ __launch_bounds__(256) void k_gates(
    const float* __restrict__ hidden,
    const float* __restrict__ cw, const float* __restrict__ cb,
    float* __restrict__ gates)
{
    int i = blockIdx.x;
    int t = threadIdx.x, wv = t >> 6, lane = t & 63;
    __shared__ float hs[HID];
    for (int c = t; c < HID; c += 256) hs[c] = hidden[(size_t)i * HID + c];
    __syncthreads();
    for (int oo = 0; oo < 12; oo++) {
        int o = wv * 12 + oo;
        const float* wr = cw + (size_t)o * HID;
        float s = 0.f;
        for (int c = lane; c < HID; c += 64) s += hs[c] * wr[c];
        s = wave_sum(s);
        if (lane == 0) {
            float x = s + cb[o];
            gates[(size_t)i * (3 * H) + o] = 1.0f / (1.0f + expf(-x));
        }
    }
}

// ---------------------------------------------------------------------------
// K6: gated combine into (N, HID) token-major buffer.
__global__ __launch_bounds__(256) void k_comb(
    const float* __restrict__ outc, const float* __restrict__ outf,
    const float* __restrict__ outs, const float* __restrict__ gates,
    float* __restrict__ comb)
{
    int i = blockIdx.x;
    int t = threadIdx.x;
    for (int c = t; c < HID; c += 256) {
        int h = c >> 6, d = c & 63;
        const float* gp = gates + (size_t)i * (3 * H) + h * 3;
        size_t off = ((size_t)h * NN + i) * D + d;
        comb[(size_t)i * HID + c] = gp[0] * outc[off] + gp[1] * outf[off] + gp[2] * outs[off];
    }
}

// ---------------------------------------------------------------------------
// K7: out = comb (N x HID) @ combine_w^T (HID x HID). Tiled fp32 GEMM.
__global__ __launch_bounds__(256) void k_gemm(
    const float* __restrict__ A, const float* __restrict__ Wt,
    float* __restrict__ out)
{
    __shared__ float As[64][65];
    __shared__ float Bs[64][65];
    int i0 = blockIdx.x * 64, o0 = blockIdx.y * 64;
    int t = threadIdx.x;
    int ty = t >> 4, tx = t & 15;
    float acc[4][4] = {};
    for (int k0 = 0; k0 < HID; k0 += 64) {
        for (int mload = 0; mload < 16; mload++) {
            int idx = t + 256 * mload;      // 0..4095
            int r = idx >> 6, c = idx & 63;
            As[r][c] = A[(size_t)(i0 + r) * HID + k0 + c];
            Bs[r][c] = Wt[(size_t)(o0 + r) * HID + k0 + c];
        }
        __syncthreads();
        for (int kk = 0; kk < 64; kk++) {
            float a[4], b[4];
            for (int u = 0; u < 4; u++) { a[u] = As[ty * 4 + u][kk]; b[u] = Bs[tx * 4 + u][kk]; }
            for (int u = 0; u < 4; u++)
                for (int w2 = 0; w2 < 4; w2++)
                    acc[u][w2] += a[u] * b[w2];
        }
        __syncthreads();
    }
    for (int u = 0; u < 4; u++)
        for (int w2 = 0; w2 < 4; w2++)
            out[(size_t)(i0 + ty * 4 + u) * HID + o0 + tx * 4 + w2] = acc[u][w2];
}

// ---------------------------------------------------------------------------
extern "C" void kernel_launch(void* const* d_in, const int* in_sizes, int n_in,
                              void* d_out, int out_size, void* d_ws, size_t ws_size,
                              hipStream_t stream)
{
    const float* hidden     = (const float*)d_in[0];
    const float* q          = (const float*)d_in[1];
    const float* k          = (const float*)d_in[2];
    const float* v          = (const float*)d_in[3];
    const float* memkv      = (const float*)d_in[4];
    const float* ksc        = (const float*)d_in[5];
    const float* vsc        = (const float*)d_in[6];
    const float* combiner_w = (const float*)d_in[7];
    const float* combiner_b = (const float*)d_in[8];
    const float* combine_w  = (const float*)d_in[9];
    float* out = (float*)d_out;

    char* ws = (char*)d_ws;
    float* ckf  = (float*)ws; ws += (size_t)HKV * (W + 1) * D * sizeof(float);
    float* cvf  = (float*)ws; ws += (size_t)HKV * (W + 1) * D * sizeof(float);
    float* outc = (float*)ws; ws += (size_t)H * NN * D * sizeof(float);
    float* outf = (float*)ws; ws += (size_t)H * NN * D * sizeof(float);
    float* outs = (float*)ws; ws += (size_t)H * NN * D * sizeof(float);
    float* gates= (float*)ws; ws += (size_t)NN * 3 * H * sizeof(float);
    float* comb = (float*)ws; ws += (size_t)NN * HID * sizeof(float);
    int*  selix = (int*)ws;   ws += (size_t)HKV * NN * NSEL * sizeof(int);

    k_compress<<<HKV * (W + 1), 64, 0, stream>>>(k, v, memkv, ksc, vsc, ckf, cvf);
    k_cattn<<<HKV * NN, 256, 0, stream>>>(q, ckf, cvf, outc, selix);
    k_selattn<<<H * NN, 64, 0, stream>>>(q, k, v, selix, outf);
    k_swin<<<H * NN, 64, 0, stream>>>(q, k, v, outs);
    k_gates<<<NN, 256, 0, stream>>>(hidden, combiner_w, combiner_b, gates);
    k_comb<<<NN, 256, 0, stream>>>(outc, outf, outs, gates, comb);
    k_gemm<<<dim3(NN / 64, HID / 64), 256, 0, stream>>>(comb, combine_w, out);
}

// Round 2
// 165.347 us; speedup vs baseline: 3.1099x; 3.1099x over previous
//
#include <hip/hip_runtime.h>
#include <hip/hip_bf16.h>
#include <math.h>

#define H    16
#define HKV  4
#define G    4
#define NN   2048
#define D    64
#define HID  1024
#define CB   16
#define W    128
#define NSEL 4
#define WIN  64
#define NEGV -1e10f
#define SCALE 0.125f

typedef __attribute__((ext_vector_type(4))) float f32x4;
typedef __attribute__((ext_vector_type(4))) short short4v;
typedef __attribute__((ext_vector_type(8))) short short8v;

__device__ inline short f2b(float x){
    __hip_bfloat16 h = __float2bfloat16(x);
    return *reinterpret_cast<short*>(&h);
}
__device__ inline float b2f(short s){
    unsigned u = ((unsigned)(unsigned short)s) << 16;
    return __builtin_bit_cast(float, u);
}
__device__ inline short8v cvt8(f32x4 a, f32x4 b){
    short8v r;
    r[0]=f2b(a[0]); r[1]=f2b(a[1]); r[2]=f2b(a[2]); r[3]=f2b(a[3]);
    r[4]=f2b(b[0]); r[5]=f2b(b[1]); r[6]=f2b(b[2]); r[7]=f2b(b[3]);
    return r;
}
#define SWZ(byte, row) ((byte) ^ (((row)&7)<<4))
#define MFMA(a,b,c) __builtin_amdgcn_mfma_f32_16x16x32_bf16(a,b,c,0,0,0)

__device__ inline float wave_sum(float x){ for(int o=32;o;o>>=1) x += __shfl_xor(x,o); return x; }
__device__ inline float wave_max(float x){ for(int o=32;o;o>>=1) x = fmaxf(x,__shfl_xor(x,o)); return x; }

__device__ inline f32x4 vmax4(f32x4 a, f32x4 b){
    f32x4 r; r[0]=fmaxf(a[0],b[0]); r[1]=fmaxf(a[1],b[1]); r[2]=fmaxf(a[2],b[2]); r[3]=fmaxf(a[3],b[3]); return r;
}
__device__ inline f32x4 shflx4(f32x4 x, int o){
    f32x4 r; r[0]=__shfl_xor(x[0],o); r[1]=__shfl_xor(x[1],o); r[2]=__shfl_xor(x[2],o); r[3]=__shfl_xor(x[3],o); return r;
}
__device__ inline f32x4 exp4(f32x4 x){
    f32x4 r; r[0]=expf(x[0]); r[1]=expf(x[1]); r[2]=expf(x[2]); r[3]=expf(x[3]); return r;
}

// ---------------------------------------------------------------------------
// q (f32) -> qb (bf16), elementwise. grid 2048 x 256, 4 elems/thread.
__global__ __launch_bounds__(256) void k_convq(const float* __restrict__ q, short* __restrict__ qb){
    int t = (blockIdx.x*256 + threadIdx.x)*4;
    f32x4 a = *(const f32x4*)(q + t);
    short4v r; r[0]=f2b(a[0]); r[1]=f2b(a[1]); r[2]=f2b(a[2]); r[3]=f2b(a[3]);
    *(short4v*)(qb + t) = r;
}

// ---------------------------------------------------------------------------
// v (f32, [hkv][N][64]) -> vT (bf16, [hkv][64][N]). LDS tile transpose.
__global__ __launch_bounds__(256) void k_vt(const float* __restrict__ v, short* __restrict__ vT){
    __shared__ float tl[64][65];
    int hk = blockIdx.y, i0 = blockIdx.x*64, t = threadIdx.x;
    for (int u=0;u<4;u++){
        int cid = t + 256*u; int r = cid>>4, ch = cid&15;
        f32x4 a = *(const f32x4*)(v + ((size_t)(hk*NN + i0 + r))*D + ch*4);
        tl[r][ch*4+0]=a[0]; tl[r][ch*4+1]=a[1]; tl[r][ch*4+2]=a[2]; tl[r][ch*4+3]=a[3];
    }
    __syncthreads();
    int d = t>>2, qd = t&3;
    short8v p0, p1;
    #pragma unroll
    for (int e=0;e<8;e++) p0[e] = f2b(tl[qd*16+e][d]);
    #pragma unroll
    for (int e=0;e<8;e++) p1[e] = f2b(tl[qd*16+8+e][d]);
    short* dst = vT + ((size_t)(hk*64 + d))*NN + i0 + qd*16;
    *(short8v*)dst = p0;
    *(short8v*)(dst+8) = p1;
}

// ---------------------------------------------------------------------------
// compressed K/V rows (bf16). ckb row-major [hkv][144][64] (rows 129..143 stay 0 via memset);
// cvt_g transposed [hkv][64][160] (cols 129..159 stay 0 via memset).
__global__ __launch_bounds__(64) void k_compress(
    const float* __restrict__ k, const float* __restrict__ v,
    const float* __restrict__ memkv, const float* __restrict__ ksc, const float* __restrict__ vsc,
    short* __restrict__ ckb, short* __restrict__ cvt_g)
{
    int bid = blockIdx.x; int hk = bid/129, j = bid%129;
    int d = threadIdx.x;
    float xk, xv;
    if (j==0){ xk = memkv[(0*HKV+hk)*D + d]; xv = memkv[(HKV+hk)*D + d]; }
    else {
        int jb = j-1;
        const float* kp = k + ((size_t)(hk*NN + jb*CB))*D + d;
        const float* vp = v + ((size_t)(hk*NN + jb*CB))*D + d;
        float sk=0.f, sv=0.f;
        #pragma unroll
        for (int tt=0;tt<CB;tt++){ sk += kp[tt*D]; sv += vp[tt*D]; }
        xk = sk*(1.0f/CB); xv = sv*(1.0f/CB);
        float msk = wave_sum(xk*xk)*(1.0f/D);
        float msv = wave_sum(xv*xv)*(1.0f/D);
        xk = xk*rsqrtf(msk+1e-6f)*ksc[d];
        xv = xv*rsqrtf(msv+1e-6f)*vsc[d];
    }
    ckb[((size_t)(hk*144 + j))*64 + d] = f2b(xk);
    cvt_g[((size_t)(hk*64 + d))*160 + j] = f2b(xv);
}

// ---------------------------------------------------------------------------
// compressed attention + importance + top-k. Block = (hk, 32 tokens), 4 waves.
// M=128 rows (token*4+head), N=144 (129 valid), K=64. Dynamic LDS 125440 B.
__global__ __launch_bounds__(256) void k_cattn(
    const short* __restrict__ qb, const short* __restrict__ ckb, const short* __restrict__ cvt_g,
    short* __restrict__ outc, int* __restrict__ selidx)
{
    extern __shared__ char smem[];
    char* aq  = smem;                      // 128 rows * 128 B = 16384
    char* ckl = smem + 16384;              // 144 rows * 128 B = 18432
    char* cvl = smem + 34816;              // 64 rows * 384 B = 24576
    char* pl  = smem + 59392;              // 128 rows * 384 B = 49152
    float* impl = (float*)(smem + 108544); // 32*128 f32 = 16384
    float* psl  = (float*)(smem + 124928); // 128 f32 = 512
    int i0 = blockIdx.x*32, hk = blockIdx.y, t = threadIdx.x;

    // stage Q: row m = tok*4+head
    for (int u=0;u<4;u++){
        int cid = t + 256*u; int row = cid>>3, ch = cid&7;
        const short* src = qb + ((size_t)((hk*G + (row&3))*NN + i0 + (row>>2)))*D + ch*8;
        *(short8v*)(aq + SWZ(row*128 + ch*16, row)) = *(const short8v*)src;
    }
    // stage CK: 144 rows
    for (int u=0;u<5;u++){
        int cid = t + 256*u;
        if (cid < 1152){
            int row = cid>>3, ch = cid&7;
            const short* src = ckb + ((size_t)(hk*144 + row))*64 + ch*8;
            *(short8v*)(ckl + SWZ(row*128 + ch*16, row)) = *(const short8v*)src;
        }
    }
    // stage CV^T: 64 rows x 24 slots (20 data incl zero-pad cols, 4 explicit zero)
    {
        int row = t>>2;
        for (int u=0;u<6;u++){
            int ch = (t&3) + 4*u;
            short8v val = (short8v)0;
            if (ch < 20) val = *(const short8v*)(cvt_g + ((size_t)(hk*64 + row))*160 + ch*8);
            *(short8v*)(cvl + SWZ(row*384 + ch*16, row)) = val;
        }
    }
    // zero P pad cols 144..191
    {
        int row = t>>1;
        for (int u=0;u<3;u++){
            int sl = (t&1)*3 + u;
            *(short8v*)(pl + SWZ(row*384 + 288 + sl*16, row)) = (short8v)0;
        }
    }
    __syncthreads();

    int w = t>>6, lane = t&63, c = lane&15, lg = lane>>4;
    f32x4 acc[2][9];
    #pragma unroll
    for (int r=0;r<2;r++)
        #pragma unroll
        for (int ct=0;ct<9;ct++) acc[r][ct] = (f32x4)0.f;

    #pragma unroll
    for (int ks=0;ks<2;ks++){
        short8v af[2];
        #pragma unroll
        for (int r=0;r<2;r++){
            int row = (w*2+r)*16 + c;
            af[r] = *(short8v*)(aq + SWZ(row*128 + ks*64 + lg*16, row));
        }
        #pragma unroll
        for (int ct=0;ct<9;ct++){
            int row = ct*16 + c;
            short8v bf = *(short8v*)(ckl + SWZ(row*128 + ks*64 + lg*16, row));
            #pragma unroll
            for (int r=0;r<2;r++) acc[r][ct] = MFMA(af[r], bf, acc[r][ct]);
        }
    }

    // scale + mask + importance + softmax + write P
    #pragma unroll
    for (int r=0;r<2;r++){
        int tloc = (w*2+r)*4 + lg;        // token within tile (regs are the 4 heads)
        int ii = i0 + tloc;
        #pragma unroll
        for (int ct=0;ct<9;ct++){
            int j = ct*16 + c;
            bool vis = (j==0) || (j<=128 && j*16 <= ii);
            f32x4 s = acc[r][ct]*SCALE;
            if (!vis){ s[0]=NEGV; s[1]=NEGV; s[2]=NEGV; s[3]=NEGV; }
            acc[r][ct] = s;
        }
        #pragma unroll
        for (int ct=0;ct<9;ct++){
            int j = ct*16 + c;
            if (j>=1 && j<=128){
                f32x4 s = acc[r][ct];
                impl[tloc*128 + (j-1)] = 0.25f*(s[0]+s[1]+s[2]+s[3]);
            }
        }
        f32x4 mx = acc[r][0];
        #pragma unroll
        for (int ct=1;ct<9;ct++) mx = vmax4(mx, acc[r][ct]);
        #pragma unroll
        for (int o=1;o<16;o<<=1) mx = vmax4(mx, shflx4(mx,o));
        f32x4 sum = (f32x4)0.f;
        #pragma unroll
        for (int ct=0;ct<9;ct++){ acc[r][ct] = exp4(acc[r][ct]-mx); sum += acc[r][ct]; }
        #pragma unroll
        for (int o=1;o<16;o<<=1) sum += shflx4(sum,o);
        #pragma unroll
        for (int ct=0;ct<9;ct++){
            #pragma unroll
            for (int reg=0;reg<4;reg++){
                int row = (w*2+r)*16 + lg*4 + reg;
                *(short*)(pl + SWZ(row*384 + (ct*16+c)*2, row)) = f2b(acc[r][ct][reg]);
            }
        }
        if (c==0){
            #pragma unroll
            for (int reg=0;reg<4;reg++) psl[(w*2+r)*16 + lg*4 + reg] = sum[reg];
        }
    }
    __syncthreads();

    // top-k (8 tokens per wave)
    #pragma unroll 1
    for (int s8=0;s8<8;s8++){
        int tt = w*8 + s8;
        float v0 = impl[tt*128 + lane];
        float v1 = impl[tt*128 + 64 + lane];
        int sel[4];
        #pragma unroll
        for (int r4=0;r4<4;r4++){
            float bv; int bj;
            if (v1 > v0){ bv=v1; bj=lane+64; } else { bv=v0; bj=lane; }
            #pragma unroll
            for (int o=32;o;o>>=1){
                float ov = __shfl_xor(bv,o);
                int oj = __shfl_xor(bj,o);
                if (ov > bv || (ov==bv && oj<bj)){ bv=ov; bj=oj; }
            }
            sel[r4]=bj;
            if (bj==lane) v0 = -INFINITY;
            else if (bj==lane+64) v1 = -INFINITY;
        }
        if (lane==0){
            int* sp = selidx + ((size_t)(hk*NN + i0 + tt))*NSEL;
            sp[0]=sel[0]; sp[1]=sel[1]; sp[2]=sel[2]; sp[3]=sel[3];
        }
    }

    // PV
    f32x4 pv[2][4];
    #pragma unroll
    for (int r=0;r<2;r++)
        #pragma unroll
        for (int ctd=0;ctd<4;ctd++) pv[r][ctd] = (f32x4)0.f;
    #pragma unroll
    for (int ks=0;ks<5;ks++){
        short8v pf[2];
        #pragma unroll
        for (int r=0;r<2;r++){
            int row = (w*2+r)*16 + c;
            pf[r] = *(short8v*)(pl + SWZ(row*384 + ks*64 + lg*16, row));
        }
        #pragma unroll
        for (int ctd=0;ctd<4;ctd++){
            int row = ctd*16 + c;
            short8v bf = *(short8v*)(cvl + SWZ(row*384 + ks*64 + lg*16, row));
            #pragma unroll
            for (int r=0;r<2;r++) pv[r][ctd] = MFMA(pf[r], bf, pv[r][ctd]);
        }
    }
    #pragma unroll
    for (int r=0;r<2;r++)
        #pragma unroll
        for (int ctd=0;ctd<4;ctd++)
            #pragma unroll
            for (int reg=0;reg<4;reg++){
                int row = (w*2+r)*16 + lg*4 + reg;
                float inv = 1.0f/psl[row];
                int hh = hk*G + reg;
                int ii = i0 + (row>>2);
                outc[((size_t)(hh*NN + ii))*D + ctd*16 + c] = f2b(pv[r][ctd][reg]*inv);
            }
}

// ---------------------------------------------------------------------------
// selected-block attention, fp32. Block = (i, hk); 4 waves = 4 heads.
__global__ __launch_bounds__(256) void k_selattn(
    const float* __restrict__ q, const float* __restrict__ k, const float* __restrict__ v,
    const int* __restrict__ selidx, short* __restrict__ outf)
{
    __shared__ char ksl[64*256];
    __shared__ float vs[64*64];
    __shared__ float qs[256];
    __shared__ float ps[256];
    __shared__ int sel_s[4];
    int i = blockIdx.x, hk = blockIdx.y, t = threadIdx.x;
    if (t < 4) sel_s[t] = selidx[((size_t)(hk*NN + i))*NSEL + t];
    __syncthreads();
    {
        int hh = t>>6, d = t&63;
        qs[t] = q[((size_t)((hk*G+hh)*NN + i))*D + d];
    }
    for (int u=0;u<4;u++){
        int cid = t + 256*u; int row = cid>>4, ch = cid&15;
        int pos = sel_s[row>>4]*CB + (row&15);
        f32x4 kk = *(const f32x4*)(k + ((size_t)(hk*NN + pos))*D + ch*4);
        *(f32x4*)(ksl + SWZ(row*256 + ch*16, row)) = kk;
        f32x4 vv = *(const f32x4*)(v + ((size_t)(hk*NN + pos))*D + ch*4);
        *(f32x4*)((char*)vs + row*256 + ch*16) = vv;
    }
    __syncthreads();
    int wv = t>>6, lane = t&63;
    f32x4 qr[16];
    #pragma unroll
    for (int d4=0;d4<16;d4++) qr[d4] = *(f32x4*)(qs + wv*64 + d4*4);
    int pos_l = sel_s[lane>>4]*CB + (lane&15);
    float s = 0.f;
    #pragma unroll
    for (int d4=0;d4<16;d4++){
        f32x4 kk = *(f32x4*)(ksl + SWZ(lane*256 + d4*16, lane));
        s += qr[d4][0]*kk[0] + qr[d4][1]*kk[1] + qr[d4][2]*kk[2] + qr[d4][3]*kk[3];
    }
    s *= SCALE;
    if (pos_l > i) s = NEGV;
    float m = wave_max(s);
    float p = expf(s - m);
    float psum = wave_sum(p);
    ps[wv*64 + lane] = p;
    __syncthreads();
    int jg = lane>>4, dg = lane&15;
    f32x4 partial = (f32x4)0.f;
    #pragma unroll
    for (int jj=0;jj<16;jj++){
        int j = jg*16 + jj;
        float pw = ps[wv*64 + j];
        f32x4 vv = *(f32x4*)(vs + j*64 + dg*4);
        partial += vv * pw;
    }
    partial += shflx4(partial, 16);
    partial += shflx4(partial, 32);
    if (lane < 16){
        float inv = 1.0f/psum;
        short4v r;
        r[0]=f2b(partial[0]*inv); r[1]=f2b(partial[1]*inv);
        r[2]=f2b(partial[2]*inv); r[3]=f2b(partial[3]*inv);
        *(short4v*)(outf + ((size_t)((hk*G+wv)*NN + i))*D + dg*4) = r;
    }
}

// ---------------------------------------------------------------------------
// sliding-window attention, bf16 MFMA. Block = (h, 64 tokens); keys pa..pa+127, pa=i0-64.
__global__ __launch_bounds__(256) void k_swin(
    const short* __restrict__ qb, const float* __restrict__ kg, const short* __restrict__ vT,
    short* __restrict__ outs)
{
    __shared__ char aq[64*128];
    __shared__ char kb[128*128];
    __shared__ char vl[64*256];
    __shared__ char pl[64*256];
    __shared__ float psl[64];
    int i0 = blockIdx.x*64, h = blockIdx.y, t = threadIdx.x;
    int hk = h >> 2;
    int pa = i0 - 64;
    for (int u=0;u<2;u++){
        int cid = t + 256*u; int row = cid>>3, ch = cid&7;
        *(short8v*)(aq + SWZ(row*128 + ch*16, row)) =
            *(const short8v*)(qb + ((size_t)(h*NN + i0 + row))*D + ch*8);
    }
    for (int u=0;u<4;u++){
        int cid = t + 256*u; int row = cid>>3, ch = cid&7;
        int pos = pa + row; pos = pos < 0 ? 0 : pos;
        const float* src = kg + ((size_t)(hk*NN + pos))*D + ch*8;
        f32x4 a = *(const f32x4*)src, b = *(const f32x4*)(src+4);
        *(short8v*)(kb + SWZ(row*128 + ch*16, row)) = cvt8(a,b);
    }
    for (int u=0;u<4;u++){
        int cid = t + 256*u; int d = cid>>4, ch = cid&15;
        int ps0 = pa + ch*8;
        short8v val;
        const short* src = vT + ((size_t)(hk*64 + d))*NN + ps0;
        if (ps0 >= 0) val = *(const short8v*)src;
        else {
            #pragma unroll
            for (int e=0;e<8;e++){ int pp = ps0+e; pp = pp<0?0:pp; val[e] = vT[((size_t)(hk*64+d))*NN + pp]; }
        }
        *(short8v*)(vl + SWZ(d*256 + ch*16, d)) = val;
    }
    __syncthreads();
    int w = t>>6, lane = t&63, c = lane&15, lg = lane>>4;
    f32x4 acc[8];
    #pragma unroll
    for (int ct=0;ct<8;ct++) acc[ct] = (f32x4)0.f;
    #pragma unroll
    for (int ks=0;ks<2;ks++){
        int arow = w*16 + c;
        short8v af = *(short8v*)(aq + SWZ(arow*128 + ks*64 + lg*16, arow));
        #pragma unroll
        for (int ct=0;ct<8;ct++){
            int brow = ct*16 + c;
            short8v bf = *(short8v*)(kb + SWZ(brow*128 + ks*64 + lg*16, brow));
            acc[ct] = MFMA(af, bf, acc[ct]);
        }
    }
    #pragma unroll
    for (int ct=0;ct<8;ct++){
        int j = ct*16 + c;
        #pragma unroll
        for (int reg=0;reg<4;reg++){
            int tl = w*16 + lg*4 + reg;
            bool vis = (j >= tl+1) && (j <= tl+64) && (pa + j >= 0);
            float s = acc[ct][reg]*SCALE;
            acc[ct][reg] = vis ? s : NEGV;
        }
    }
    f32x4 mx = acc[0];
    #pragma unroll
    for (int ct=1;ct<8;ct++) mx = vmax4(mx, acc[ct]);
    #pragma unroll
    for (int o=1;o<16;o<<=1) mx = vmax4(mx, shflx4(mx,o));
    f32x4 sum = (f32x4)0.f;
    #pragma unroll
    for (int ct=0;ct<8;ct++){ acc[ct] = exp4(acc[ct]-mx); sum += acc[ct]; }
    #pragma unroll
    for (int o=1;o<16;o<<=1) sum += shflx4(sum,o);
    #pragma unroll
    for (int ct=0;ct<8;ct++){
        #pragma unroll
        for (int reg=0;reg<4;reg++){
            int row = w*16 + lg*4 + reg;
            *(short*)(pl + SWZ(row*256 + (ct*16+c)*2, row)) = f2b(acc[ct][reg]);
        }
    }
    if (c==0){
        #pragma unroll
        for (int reg=0;reg<4;reg++) psl[w*16+lg*4+reg] = sum[reg];
    }
    __syncthreads();
    f32x4 pv[4];
    #pragma unroll
    for (int ctd=0;ctd<4;ctd++) pv[ctd] = (f32x4)0.f;
    #pragma unroll
    for (int ks=0;ks<4;ks++){
        int arow = w*16 + c;
        short8v pf = *(short8v*)(pl + SWZ(arow*256 + ks*64 + lg*16, arow));
        #pragma unroll
        for (int ctd=0;ctd<4;ctd++){
            int brow = ctd*16 + c;
            short8v bf = *(short8v*)(vl + SWZ(brow*256 + ks*64 + lg*16, brow));
            pv[ctd] = MFMA(pf, bf, pv[ctd]);
        }
    }
    #pragma unroll
    for (int ctd=0;ctd<4;ctd++)
        #pragma unroll
        for (int reg=0;reg<4;reg++){
            int row = w*16 + lg*4 + reg;
            float inv = 1.0f/psl[row];
            outs[((size_t)(h*NN + i0 + row))*D + ctd*16 + c] = f2b(pv[ctd][reg]*inv);
        }
}

// ---------------------------------------------------------------------------
// gates = sigmoid(hidden @ cw^T + cb), bf16 MFMA. Block = 64 tokens; N=48.
__global__ __launch_bounds__(256) void k_gates(
    const float* __restrict__ hidden, const float* __restrict__ cw, const float* __restrict__ cb,
    float* __restrict__ gates)
{
    __shared__ char ha[64*128];
    int i0 = blockIdx.x*64, t = threadIdx.x;
    int w = t>>6, lane = t&63, c = lane&15, lg = lane>>4;
    f32x4 acc[3];
    #pragma unroll
    for (int ct=0;ct<3;ct++) acc[ct] = (f32x4)0.f;
    for (int kc=0;kc<16;kc++){
        if (kc) __syncthreads();
        for (int u=0;u<2;u++){
            int cid = t + 256*u; int row = cid>>3, ch = cid&7;
            const float* src = hidden + ((size_t)(i0+row))*HID + kc*64 + ch*8;
            f32x4 a = *(const f32x4*)src, b = *(const f32x4*)(src+4);
            *(short8v*)(ha + SWZ(row*128 + ch*16, row)) = cvt8(a,b);
        }
        __syncthreads();
        #pragma unroll
        for (int ks=0;ks<2;ks++){
            int arow = w*16 + c;
            short8v af = *(short8v*)(ha + SWZ(arow*128 + ks*64 + lg*16, arow));
            #pragma unroll
            for (int ct=0;ct<3;ct++){
                int o = ct*16 + c;
                const float* bsrc = cw + (size_t)o*HID + kc*64 + ks*32 + lg*8;
                f32x4 b0 = *(const f32x4*)bsrc, b1 = *(const f32x4*)(bsrc+4);
                acc[ct] = MFMA(af, cvt8(b0,b1), acc[ct]);
            }
        }
    }
    #pragma unroll
    for (int ct=0;ct<3;ct++){
        int o = ct*16 + c;
        float bias = cb[o];
        #pragma unroll
        for (int reg=0;reg<4;reg++){
            int row = w*16 + lg*4 + reg;
            float x = acc[ct][reg] + bias;
            gates[(size_t)(i0+row)*48 + o] = 1.0f/(1.0f+expf(-x));
        }
    }
}

// ---------------------------------------------------------------------------
// gated combine -> comb (bf16, token-major [N][HID])
__global__ __launch_bounds__(256) void k_comb(
    const short* __restrict__ outc, const short* __restrict__ outf, const short* __restrict__ outs_,
    const float* __restrict__ gates, short* __restrict__ comb)
{
    int i = blockIdx.x, t = threadIdx.x;
    int hh = t>>4, d0 = (t&15)*4;
    const float* gp = gates + (size_t)i*48 + hh*3;
    float g0 = gp[0], g1 = gp[1], g2 = gp[2];
    size_t off = ((size_t)(hh*NN + i))*D + d0;
    short4v a = *(const short4v*)(outc + off);
    short4v b = *(const short4v*)(outf + off);
    short4v cc = *(const short4v*)(outs_ + off);
    short4v r;
    #pragma unroll
    for (int e=0;e<4;e++) r[e] = f2b(g0*b2f(a[e]) + g1*b2f(b[e]) + g2*b2f(cc[e]));
    *(short4v*)(comb + (size_t)i*HID + t*4) = r;
}

// ---------------------------------------------------------------------------
// out = comb (bf16 2048x1024) @ combine_w^T (f32->bf16 1024x1024), f32 out.
__global__ __launch_bounds__(256) void k_gemm(
    const short* __restrict__ A, const float* __restrict__ Bw, float* __restrict__ out)
{
    __shared__ char ab[64*128];
    __shared__ char bb[128*128];
    int m0 = blockIdx.x*64, n0 = blockIdx.y*128, t = threadIdx.x;
    int w = t>>6, lane = t&63, c = lane&15, lg = lane>>4;
    f32x4 acc[8];
    #pragma unroll
    for (int ct=0;ct<8;ct++) acc[ct] = (f32x4)0.f;
    for (int kc=0;kc<16;kc++){
        if (kc) __syncthreads();
        for (int u=0;u<2;u++){
            int cid = t + 256*u; int row = cid>>3, ch = cid&7;
            *(short8v*)(ab + SWZ(row*128 + ch*16, row)) =
                *(const short8v*)(A + ((size_t)(m0+row))*HID + kc*64 + ch*8);
        }
        for (int u=0;u<4;u++){
            int cid = t + 256*u; int row = cid>>3, ch = cid&7;
            const float* src = Bw + ((size_t)(n0+row))*HID + kc*64 + ch*8;
            f32x4 a0 = *(const f32x4*)src, a1 = *(const f32x4*)(src+4);
            *(short8v*)(bb + SWZ(row*128 + ch*16, row)) = cvt8(a0,a1);
        }
        __syncthreads();
        #pragma unroll
        for (int ks=0;ks<2;ks++){
            int arow = w*16 + c;
            short8v af = *(short8v*)(ab + SWZ(arow*128 + ks*64 + lg*16, arow));
            #pragma unroll
            for (int ct=0;ct<8;ct++){
                int brow = ct*16 + c;
                short8v bf = *(short8v*)(bb + SWZ(brow*128 + ks*64 + lg*16, brow));
                acc[ct] = MFMA(af, bf, acc[ct]);
            }
        }
    }
    #pragma unroll
    for (int ct=0;ct<8;ct++)
        #pragma unroll
        for (int reg=0;reg<4;reg++){
            int row = w*16 + lg*4 + reg;
            out[((size_t)(m0+row))*HID + n0 + ct*16 + c] = acc[ct][reg];
        }
}

// ---------------------------------------------------------------------------
extern "C" void kernel_launch(void* const* d_in, const int* in_sizes, int n_in,
                              void* d_out, int out_size, void* d_ws, size_t ws_size,
                              hipStream_t stream)
{
    const float* hidden     = (const float*)d_in[0];
    const float* q          = (const float*)d_in[1];
    const float* k          = (const float*)d_in[2];
    const float* v          = (const float*)d_in[3];
    const float* memkv      = (const float*)d_in[4];
    const float* ksc        = (const float*)d_in[5];
    const float* vsc        = (const float*)d_in[6];
    const float* combiner_w = (const float*)d_in[7];
    const float* combiner_b = (const float*)d_in[8];
    const float* combine_w  = (const float*)d_in[9];
    float* out = (float*)d_out;

    char* p = (char*)d_ws;
    short* ckb  = (short*)p; p += (size_t)HKV*144*64*2;      // 73728
    short* cvtg = (short*)p; p += (size_t)HKV*64*160*2;      // 81920
    short* qbg  = (short*)p; p += (size_t)H*NN*D*2;          // 4 MB
    short* vTg  = (short*)p; p += (size_t)HKV*64*NN*2;       // 1 MB
    short* outc = (short*)p; p += (size_t)H*NN*D*2;          // 4 MB
    short* outf = (short*)p; p += (size_t)H*NN*D*2;          // 4 MB
    short* outs = (short*)p; p += (size_t)H*NN*D*2;          // 4 MB
    float* gates= (float*)p; p += (size_t)NN*48*4;           // 393216
    short* comb = (short*)p; p += (size_t)NN*HID*2;          // 4 MB
    int*  selix = (int*)p;   p += (size_t)HKV*NN*NSEL*4;     // 131072

    hipFuncSetAttribute((const void*)k_cattn, hipFuncAttributeMaxDynamicSharedMemorySize, 125440);
    hipMemsetAsync(d_ws, 0, (size_t)HKV*144*64*2 + (size_t)HKV*64*160*2, stream);

    k_convq   <<<2048, 256, 0, stream>>>(q, qbg);
    k_vt      <<<dim3(NN/64, HKV), 256, 0, stream>>>(v, vTg);
    k_compress<<<HKV*129, 64, 0, stream>>>(k, v, memkv, ksc, vsc, ckb, cvtg);
    k_cattn   <<<dim3(NN/32, HKV), 256, 125440, stream>>>(qbg, ckb, cvtg, outc, selix);
    k_selattn <<<dim3(NN, HKV), 256, 0, stream>>>(q, k, v, selix, outf);
    k_swin    <<<dim3(NN/64, H), 256, 0, stream>>>(qbg, k, vTg, outs);
    k_gates   <<<NN/64, 256, 0, stream>>>(hidden, combiner_w, combiner_b, gates);
    k_comb    <<<NN, 256, 0, stream>>>(outc, outf, outs, gates, comb);
    k_gemm    <<<dim3(NN/64, HID/128), 256, 0, stream>>>(comb, combine_w, out);
}

// Round 3
// 107.296 us; speedup vs baseline: 4.7924x; 1.5410x over previous
//
#include <hip/hip_runtime.h>
#include <hip/hip_bf16.h>
#include <math.h>

#define H    16
#define HKV  4
#define G    4
#define NN   2048
#define D    64
#define HID  1024
#define CB   16
#define W    128
#define NSEL 4
#define WIN  64
#define NEGV -1e10f
#define SCALE 0.125f

typedef __attribute__((ext_vector_type(4))) float f32x4;
typedef __attribute__((ext_vector_type(4))) short short4v;
typedef __attribute__((ext_vector_type(8))) short short8v;

__device__ inline short f2b(float x){
    __hip_bfloat16 h = __float2bfloat16(x);
    return *reinterpret_cast<short*>(&h);
}
__device__ inline float b2f(short s){
    unsigned u = ((unsigned)(unsigned short)s) << 16;
    return __builtin_bit_cast(float, u);
}
__device__ inline short8v cvt8(f32x4 a, f32x4 b){
    short8v r;
    r[0]=f2b(a[0]); r[1]=f2b(a[1]); r[2]=f2b(a[2]); r[3]=f2b(a[3]);
    r[4]=f2b(b[0]); r[5]=f2b(b[1]); r[6]=f2b(b[2]); r[7]=f2b(b[3]);
    return r;
}
#define SWZ(byte, row) ((byte) ^ (((row)&7)<<4))
#define MFMA(a,b,c) __builtin_amdgcn_mfma_f32_16x16x32_bf16(a,b,c,0,0,0)

__device__ inline float wave_sum(float x){ for(int o=32;o;o>>=1) x += __shfl_xor(x,o); return x; }
__device__ inline float wave_max(float x){ for(int o=32;o;o>>=1) x = fmaxf(x,__shfl_xor(x,o)); return x; }

__device__ inline f32x4 vmax4(f32x4 a, f32x4 b){
    f32x4 r; r[0]=fmaxf(a[0],b[0]); r[1]=fmaxf(a[1],b[1]); r[2]=fmaxf(a[2],b[2]); r[3]=fmaxf(a[3],b[3]); return r;
}
__device__ inline f32x4 shflx4(f32x4 x, int o){
    f32x4 r; r[0]=__shfl_xor(x[0],o); r[1]=__shfl_xor(x[1],o); r[2]=__shfl_xor(x[2],o); r[3]=__shfl_xor(x[3],o); return r;
}
__device__ inline f32x4 exp4(f32x4 x){
    f32x4 r; r[0]=expf(x[0]); r[1]=expf(x[1]); r[2]=expf(x[2]); r[3]=expf(x[3]); return r;
}

// ---------------------------------------------------------------------------
// fused prep: f32->bf16 converts (q, hidden, combine_w, combiner_w, k), V transpose,
// compressed K/V. Block-range dispatch.
__device__ inline void conv_seg(const float* __restrict__ src, short* __restrict__ dst,
                                int b, int t){
    size_t idx = (size_t)b*1024 + t*4;
    f32x4 a = *(const f32x4*)(src + idx);
    short4v r; r[0]=f2b(a[0]); r[1]=f2b(a[1]); r[2]=f2b(a[2]); r[3]=f2b(a[3]);
    *(short4v*)(dst + idx) = r;
}

__global__ __launch_bounds__(256) void k_prep(
    const float* __restrict__ q, const float* __restrict__ hidden,
    const float* __restrict__ combine_w, const float* __restrict__ combiner_w,
    const float* __restrict__ k, const float* __restrict__ v,
    const float* __restrict__ memkv, const float* __restrict__ ksc, const float* __restrict__ vsc,
    short* __restrict__ qb, short* __restrict__ hb, short* __restrict__ wb,
    short* __restrict__ cwb, short* __restrict__ kb16, short* __restrict__ vT,
    short* __restrict__ ckb, short* __restrict__ cvtg)
{
    int b = blockIdx.x, t = threadIdx.x;
    if (b < 2048){ conv_seg(q, qb, b, t); return; }
    b -= 2048;
    if (b < 2048){ conv_seg(hidden, hb, b, t); return; }
    b -= 2048;
    if (b < 1024){ conv_seg(combine_w, wb, b, t); return; }
    b -= 1024;
    if (b < 48){ conv_seg(combiner_w, cwb, b, t); return; }
    b -= 48;
    if (b < 512){ conv_seg(k, kb16, b, t); return; }
    b -= 512;
    if (b < 128){
        // V transpose: vT[hk][d][i]
        __shared__ float tl[64][65];
        int hk = b>>5, i0 = (b&31)*64;
        for (int u=0;u<4;u++){
            int cid = t + 256*u; int r = cid>>4, ch = cid&15;
            f32x4 a = *(const f32x4*)(v + ((size_t)(hk*NN + i0 + r))*D + ch*4);
            tl[r][ch*4+0]=a[0]; tl[r][ch*4+1]=a[1]; tl[r][ch*4+2]=a[2]; tl[r][ch*4+3]=a[3];
        }
        __syncthreads();
        int d = t>>2, qd = t&3;
        short8v p0, p1;
        #pragma unroll
        for (int e=0;e<8;e++) p0[e] = f2b(tl[qd*16+e][d]);
        #pragma unroll
        for (int e=0;e<8;e++) p1[e] = f2b(tl[qd*16+8+e][d]);
        short* dst = vT + ((size_t)(hk*64 + d))*NN + i0 + qd*16;
        *(short8v*)dst = p0;
        *(short8v*)(dst+8) = p1;
        return;
    }
    b -= 128;
    {
        // compressed rows: j = b (0..128), 4 waves = 4 hk
        int j = b;
        int hk = t>>6, d = t&63;
        float xk, xv;
        if (j==0){ xk = memkv[(0*HKV+hk)*D + d]; xv = memkv[(HKV+hk)*D + d]; }
        else {
            int jb = j-1;
            const float* kp = k + ((size_t)(hk*NN + jb*CB))*D + d;
            const float* vp = v + ((size_t)(hk*NN + jb*CB))*D + d;
            float sk=0.f, sv=0.f;
            #pragma unroll
            for (int tt=0;tt<CB;tt++){ sk += kp[tt*D]; sv += vp[tt*D]; }
            xk = sk*(1.0f/CB); xv = sv*(1.0f/CB);
            float msk = wave_sum(xk*xk)*(1.0f/D);
            float msv = wave_sum(xv*xv)*(1.0f/D);
            xk = xk*rsqrtf(msk+1e-6f)*ksc[d];
            xv = xv*rsqrtf(msv+1e-6f)*vsc[d];
        }
        ckb[((size_t)(hk*144 + j))*64 + d] = f2b(xk);
        cvtg[((size_t)(hk*64 + d))*160 + j] = f2b(xv);
    }
}

// ---------------------------------------------------------------------------
// compressed attention + importance + top-k. Block = (hk, 32 tokens), 4 waves.
__global__ __launch_bounds__(256) void k_cattn(
    const short* __restrict__ qb, const short* __restrict__ ckb, const short* __restrict__ cvt_g,
    short* __restrict__ outc, int* __restrict__ selidx)
{
    extern __shared__ char smem[];
    char* aq  = smem;                      // 128 * 128
    char* ckl = smem + 16384;              // 144 * 128
    char* cvl = smem + 34816;              // 64 * 384
    char* pl  = smem + 59392;              // 128 * 384
    float* impl = (float*)(smem + 108544); // 32*128 f32
    float* psl  = (float*)(smem + 124928); // 128 f32
    int i0 = blockIdx.x*32, hk = blockIdx.y, t = threadIdx.x;

    for (int u=0;u<4;u++){
        int cid = t + 256*u; int row = cid>>3, ch = cid&7;
        const short* src = qb + ((size_t)((hk*G + (row&3))*NN + i0 + (row>>2)))*D + ch*8;
        *(short8v*)(aq + SWZ(row*128 + ch*16, row)) = *(const short8v*)src;
    }
    for (int u=0;u<5;u++){
        int cid = t + 256*u;
        if (cid < 1152){
            int row = cid>>3, ch = cid&7;
            const short* src = ckb + ((size_t)(hk*144 + row))*64 + ch*8;
            *(short8v*)(ckl + SWZ(row*128 + ch*16, row)) = *(const short8v*)src;
        }
    }
    {
        int row = t>>2;
        for (int u=0;u<6;u++){
            int ch = (t&3) + 4*u;
            short8v val = (short8v)0;
            if (ch < 20) val = *(const short8v*)(cvt_g + ((size_t)(hk*64 + row))*160 + ch*8);
            *(short8v*)(cvl + SWZ(row*384 + ch*16, row)) = val;
        }
    }
    {
        int row = t>>1;
        for (int u=0;u<3;u++){
            int sl = (t&1)*3 + u;
            *(short8v*)(pl + SWZ(row*384 + 288 + sl*16, row)) = (short8v)0;
        }
    }
    __syncthreads();

    int w = t>>6, lane = t&63, c = lane&15, lg = lane>>4;
    f32x4 acc[2][9];
    #pragma unroll
    for (int r=0;r<2;r++)
        #pragma unroll
        for (int ct=0;ct<9;ct++) acc[r][ct] = (f32x4)0.f;

    #pragma unroll
    for (int ks=0;ks<2;ks++){
        short8v af[2];
        #pragma unroll
        for (int r=0;r<2;r++){
            int row = (w*2+r)*16 + c;
            af[r] = *(short8v*)(aq + SWZ(row*128 + ks*64 + lg*16, row));
        }
        #pragma unroll
        for (int ct=0;ct<9;ct++){
            int row = ct*16 + c;
            short8v bf = *(short8v*)(ckl + SWZ(row*128 + ks*64 + lg*16, row));
            #pragma unroll
            for (int r=0;r<2;r++) acc[r][ct] = MFMA(af[r], bf, acc[r][ct]);
        }
    }

    #pragma unroll
    for (int r=0;r<2;r++){
        int tloc = (w*2+r)*4 + lg;
        int ii = i0 + tloc;
        #pragma unroll
        for (int ct=0;ct<9;ct++){
            int j = ct*16 + c;
            bool vis = (j==0) || (j<=128 && j*16 <= ii);
            f32x4 s = acc[r][ct]*SCALE;
            if (!vis){ s[0]=NEGV; s[1]=NEGV; s[2]=NEGV; s[3]=NEGV; }
            acc[r][ct] = s;
        }
        #pragma unroll
        for (int ct=0;ct<9;ct++){
            int j = ct*16 + c;
            if (j>=1 && j<=128){
                f32x4 s = acc[r][ct];
                impl[tloc*128 + (j-1)] = 0.25f*(s[0]+s[1]+s[2]+s[3]);
            }
        }
        f32x4 mx = acc[r][0];
        #pragma unroll
        for (int ct=1;ct<9;ct++) mx = vmax4(mx, acc[r][ct]);
        #pragma unroll
        for (int o=1;o<16;o<<=1) mx = vmax4(mx, shflx4(mx,o));
        f32x4 sum = (f32x4)0.f;
        #pragma unroll
        for (int ct=0;ct<9;ct++){ acc[r][ct] = exp4(acc[r][ct]-mx); sum += acc[r][ct]; }
        #pragma unroll
        for (int o=1;o<16;o<<=1) sum += shflx4(sum,o);
        #pragma unroll
        for (int ct=0;ct<9;ct++){
            #pragma unroll
            for (int reg=0;reg<4;reg++){
                int row = (w*2+r)*16 + lg*4 + reg;
                *(short*)(pl + SWZ(row*384 + (ct*16+c)*2, row)) = f2b(acc[r][ct][reg]);
            }
        }
        if (c==0){
            #pragma unroll
            for (int reg=0;reg<4;reg++) psl[(w*2+r)*16 + lg*4 + reg] = sum[reg];
        }
    }
    __syncthreads();

    #pragma unroll 1
    for (int s8=0;s8<8;s8++){
        int tt = w*8 + s8;
        float v0 = impl[tt*128 + lane];
        float v1 = impl[tt*128 + 64 + lane];
        int sel[4];
        #pragma unroll
        for (int r4=0;r4<4;r4++){
            float bv; int bj;
            if (v1 > v0){ bv=v1; bj=lane+64; } else { bv=v0; bj=lane; }
            #pragma unroll
            for (int o=32;o;o>>=1){
                float ov = __shfl_xor(bv,o);
                int oj = __shfl_xor(bj,o);
                if (ov > bv || (ov==bv && oj<bj)){ bv=ov; bj=oj; }
            }
            sel[r4]=bj;
            if (bj==lane) v0 = -INFINITY;
            else if (bj==lane+64) v1 = -INFINITY;
        }
        if (lane==0){
            int* sp = selidx + ((size_t)(hk*NN + i0 + tt))*NSEL;
            sp[0]=sel[0]; sp[1]=sel[1]; sp[2]=sel[2]; sp[3]=sel[3];
        }
    }

    f32x4 pv[2][4];
    #pragma unroll
    for (int r=0;r<2;r++)
        #pragma unroll
        for (int ctd=0;ctd<4;ctd++) pv[r][ctd] = (f32x4)0.f;
    #pragma unroll
    for (int ks=0;ks<5;ks++){
        short8v pf[2];
        #pragma unroll
        for (int r=0;r<2;r++){
            int row = (w*2+r)*16 + c;
            pf[r] = *(short8v*)(pl + SWZ(row*384 + ks*64 + lg*16, row));
        }
        #pragma unroll
        for (int ctd=0;ctd<4;ctd++){
            int row = ctd*16 + c;
            short8v bf = *(short8v*)(cvl + SWZ(row*384 + ks*64 + lg*16, row));
            #pragma unroll
            for (int r=0;r<2;r++) pv[r][ctd] = MFMA(pf[r], bf, pv[r][ctd]);
        }
    }
    #pragma unroll
    for (int r=0;r<2;r++)
        #pragma unroll
        for (int ctd=0;ctd<4;ctd++)
            #pragma unroll
            for (int reg=0;reg<4;reg++){
                int row = (w*2+r)*16 + lg*4 + reg;
                float inv = 1.0f/psl[row];
                int hh = hk*G + reg;
                int ii = i0 + (row>>2);
                outc[((size_t)(hh*NN + ii))*D + ctd*16 + c] = f2b(pv[r][ctd][reg]*inv);
            }
}

// ---------------------------------------------------------------------------
// selected-block attention, fp32. Block = (i, hk); 4 waves = 4 heads.
__global__ __launch_bounds__(256) void k_selattn(
    const float* __restrict__ q, const float* __restrict__ k, const float* __restrict__ v,
    const int* __restrict__ selidx, short* __restrict__ outf)
{
    __shared__ char ksl[64*256];
    __shared__ float vs[64*64];
    __shared__ float qs[256];
    __shared__ float ps[256];
    __shared__ int sel_s[4];
    int i = blockIdx.x, hk = blockIdx.y, t = threadIdx.x;
    if (t < 4) sel_s[t] = selidx[((size_t)(hk*NN + i))*NSEL + t];
    __syncthreads();
    {
        int hh = t>>6, d = t&63;
        qs[t] = q[((size_t)((hk*G+hh)*NN + i))*D + d];
    }
    for (int u=0;u<4;u++){
        int cid = t + 256*u; int row = cid>>4, ch = cid&15;
        int pos = sel_s[row>>4]*CB + (row&15);
        f32x4 kk = *(const f32x4*)(k + ((size_t)(hk*NN + pos))*D + ch*4);
        *(f32x4*)(ksl + SWZ(row*256 + ch*16, row)) = kk;
        f32x4 vv = *(const f32x4*)(v + ((size_t)(hk*NN + pos))*D + ch*4);
        *(f32x4*)((char*)vs + row*256 + ch*16) = vv;
    }
    __syncthreads();
    int wv = t>>6, lane = t&63;
    f32x4 qr[16];
    #pragma unroll
    for (int d4=0;d4<16;d4++) qr[d4] = *(f32x4*)(qs + wv*64 + d4*4);
    int pos_l = sel_s[lane>>4]*CB + (lane&15);
    float s = 0.f;
    #pragma unroll
    for (int d4=0;d4<16;d4++){
        f32x4 kk = *(f32x4*)(ksl + SWZ(lane*256 + d4*16, lane));
        s += qr[d4][0]*kk[0] + qr[d4][1]*kk[1] + qr[d4][2]*kk[2] + qr[d4][3]*kk[3];
    }
    s *= SCALE;
    if (pos_l > i) s = NEGV;
    float m = wave_max(s);
    float p = expf(s - m);
    float psum = wave_sum(p);
    ps[wv*64 + lane] = p;
    __syncthreads();
    int jg = lane>>4, dg = lane&15;
    f32x4 partial = (f32x4)0.f;
    #pragma unroll
    for (int jj=0;jj<16;jj++){
        int j = jg*16 + jj;
        float pw = ps[wv*64 + j];
        f32x4 vv = *(f32x4*)(vs + j*64 + dg*4);
        partial += vv * pw;
    }
    partial += shflx4(partial, 16);
    partial += shflx4(partial, 32);
    if (lane < 16){
        float inv = 1.0f/psum;
        short4v r;
        r[0]=f2b(partial[0]*inv); r[1]=f2b(partial[1]*inv);
        r[2]=f2b(partial[2]*inv); r[3]=f2b(partial[3]*inv);
        *(short4v*)(outf + ((size_t)((hk*G+wv)*NN + i))*D + dg*4) = r;
    }
}

// ---------------------------------------------------------------------------
// sliding-window attention, bf16 MFMA. Block = (h, 64 tokens); keys pa..pa+127.
__global__ __launch_bounds__(256) void k_swin(
    const short* __restrict__ qb, const short* __restrict__ kb16, const short* __restrict__ vT,
    short* __restrict__ outs)
{
    __shared__ char aq[64*128];
    __shared__ char kb[128*128];
    __shared__ char vl[64*256];
    __shared__ char pl[64*256];
    __shared__ float psl[64];
    int i0 = blockIdx.x*64, h = blockIdx.y, t = threadIdx.x;
    int hk = h >> 2;
    int pa = i0 - 64;
    for (int u=0;u<2;u++){
        int cid = t + 256*u; int row = cid>>3, ch = cid&7;
        *(short8v*)(aq + SWZ(row*128 + ch*16, row)) =
            *(const short8v*)(qb + ((size_t)(h*NN + i0 + row))*D + ch*8);
    }
    for (int u=0;u<4;u++){
        int cid = t + 256*u; int row = cid>>3, ch = cid&7;
        int pos = pa + row; pos = pos < 0 ? 0 : pos;
        *(short8v*)(kb + SWZ(row*128 + ch*16, row)) =
            *(const short8v*)(kb16 + ((size_t)(hk*NN + pos))*D + ch*8);
    }
    for (int u=0;u<4;u++){
        int cid = t + 256*u; int d = cid>>4, ch = cid&15;
        int ps0 = pa + ch*8;
        short8v val;
        const short* src = vT + ((size_t)(hk*64 + d))*NN + ps0;
        if (ps0 >= 0) val = *(const short8v*)src;
        else {
            #pragma unroll
            for (int e=0;e<8;e++){ int pp = ps0+e; pp = pp<0?0:pp; val[e] = vT[((size_t)(hk*64+d))*NN + pp]; }
        }
        *(short8v*)(vl + SWZ(d*256 + ch*16, d)) = val;
    }
    __syncthreads();
    int w = t>>6, lane = t&63, c = lane&15, lg = lane>>4;
    f32x4 acc[8];
    #pragma unroll
    for (int ct=0;ct<8;ct++) acc[ct] = (f32x4)0.f;
    #pragma unroll
    for (int ks=0;ks<2;ks++){
        int arow = w*16 + c;
        short8v af = *(short8v*)(aq + SWZ(arow*128 + ks*64 + lg*16, arow));
        #pragma unroll
        for (int ct=0;ct<8;ct++){
            int brow = ct*16 + c;
            short8v bf = *(short8v*)(kb + SWZ(brow*128 + ks*64 + lg*16, brow));
            acc[ct] = MFMA(af, bf, acc[ct]);
        }
    }
    #pragma unroll
    for (int ct=0;ct<8;ct++){
        int j = ct*16 + c;
        #pragma unroll
        for (int reg=0;reg<4;reg++){
            int tl = w*16 + lg*4 + reg;
            bool vis = (j >= tl+1) && (j <= tl+64) && (pa + j >= 0);
            float s = acc[ct][reg]*SCALE;
            acc[ct][reg] = vis ? s : NEGV;
        }
    }
    f32x4 mx = acc[0];
    #pragma unroll
    for (int ct=1;ct<8;ct++) mx = vmax4(mx, acc[ct]);
    #pragma unroll
    for (int o=1;o<16;o<<=1) mx = vmax4(mx, shflx4(mx,o));
    f32x4 sum = (f32x4)0.f;
    #pragma unroll
    for (int ct=0;ct<8;ct++){ acc[ct] = exp4(acc[ct]-mx); sum += acc[ct]; }
    #pragma unroll
    for (int o=1;o<16;o<<=1) sum += shflx4(sum,o);
    #pragma unroll
    for (int ct=0;ct<8;ct++){
        #pragma unroll
        for (int reg=0;reg<4;reg++){
            int row = w*16 + lg*4 + reg;
            *(short*)(pl + SWZ(row*256 + (ct*16+c)*2, row)) = f2b(acc[ct][reg]);
        }
    }
    if (c==0){
        #pragma unroll
        for (int reg=0;reg<4;reg++) psl[w*16+lg*4+reg] = sum[reg];
    }
    __syncthreads();
    f32x4 pv[4];
    #pragma unroll
    for (int ctd=0;ctd<4;ctd++) pv[ctd] = (f32x4)0.f;
    #pragma unroll
    for (int ks=0;ks<4;ks++){
        int arow = w*16 + c;
        short8v pf = *(short8v*)(pl + SWZ(arow*256 + ks*64 + lg*16, arow));
        #pragma unroll
        for (int ctd=0;ctd<4;ctd++){
            int brow = ctd*16 + c;
            short8v bf = *(short8v*)(vl + SWZ(brow*256 + ks*64 + lg*16, brow));
            pv[ctd] = MFMA(pf, bf, pv[ctd]);
        }
    }
    #pragma unroll
    for (int ctd=0;ctd<4;ctd++)
        #pragma unroll
        for (int reg=0;reg<4;reg++){
            int row = w*16 + lg*4 + reg;
            float inv = 1.0f/psl[row];
            outs[((size_t)(h*NN + i0 + row))*D + ctd*16 + c] = f2b(pv[ctd][reg]*inv);
        }
}

// ---------------------------------------------------------------------------
// gates split-K partial GEMM: gpart[ky][token][48] = hb(64 tok) @ cwb^T over K-chunk ky.
__global__ __launch_bounds__(256) void k_gates(
    const short* __restrict__ hb, const short* __restrict__ cwb, float* __restrict__ gpart)
{
    __shared__ char ha[64*128];
    __shared__ char bl[48*128];
    int i0 = blockIdx.x*64, ky = blockIdx.y, t = threadIdx.x;
    int w = t>>6, lane = t&63, c = lane&15, lg = lane>>4;
    f32x4 acc[3];
    #pragma unroll
    for (int ct=0;ct<3;ct++) acc[ct] = (f32x4)0.f;
    for (int kc=0;kc<4;kc++){
        int kbase = ky*256 + kc*64;
        if (kc) __syncthreads();
        for (int u=0;u<2;u++){
            int cid = t + 256*u; int row = cid>>3, ch = cid&7;
            *(short8v*)(ha + SWZ(row*128 + ch*16, row)) =
                *(const short8v*)(hb + (size_t)(i0+row)*HID + kbase + ch*8);
        }
        for (int u=0;u<2;u++){
            int cid = t + 256*u;
            if (cid < 384){
                int row = cid>>3, ch = cid&7;
                *(short8v*)(bl + SWZ(row*128 + ch*16, row)) =
                    *(const short8v*)(cwb + (size_t)row*HID + kbase + ch*8);
            }
        }
        __syncthreads();
        #pragma unroll
        for (int ks=0;ks<2;ks++){
            int arow = w*16 + c;
            short8v af = *(short8v*)(ha + SWZ(arow*128 + ks*64 + lg*16, arow));
            #pragma unroll
            for (int ct=0;ct<3;ct++){
                int brow = ct*16 + c;
                short8v bf = *(short8v*)(bl + SWZ(brow*128 + ks*64 + lg*16, brow));
                acc[ct] = MFMA(af, bf, acc[ct]);
            }
        }
    }
    #pragma unroll
    for (int ct=0;ct<3;ct++)
        #pragma unroll
        for (int reg=0;reg<4;reg++){
            int row = w*16 + lg*4 + reg;
            gpart[((size_t)ky*NN + i0 + row)*48 + ct*16 + c] = acc[ct][reg];
        }
}

// ---------------------------------------------------------------------------
// gated combine (sums gate partials + bias + sigmoid in-block) -> comb bf16 [N][HID]
__global__ __launch_bounds__(256) void k_comb(
    const short* __restrict__ outc, const short* __restrict__ outf, const short* __restrict__ outs_,
    const float* __restrict__ gpart, const float* __restrict__ cb, short* __restrict__ comb)
{
    __shared__ float gs[48];
    int i = blockIdx.x, t = threadIdx.x;
    if (t < 48){
        float s = gpart[(size_t)0*NN*48 + i*48 + t] + gpart[(size_t)1*NN*48 + i*48 + t]
                + gpart[(size_t)2*NN*48 + i*48 + t] + gpart[(size_t)3*NN*48 + i*48 + t] + cb[t];
        gs[t] = 1.0f/(1.0f+expf(-s));
    }
    __syncthreads();
    int hh = t>>4, d0 = (t&15)*4;
    float g0 = gs[hh*3], g1 = gs[hh*3+1], g2 = gs[hh*3+2];
    size_t off = ((size_t)(hh*NN + i))*D + d0;
    short4v a = *(const short4v*)(outc + off);
    short4v b = *(const short4v*)(outf + off);
    short4v cc = *(const short4v*)(outs_ + off);
    short4v r;
    #pragma unroll
    for (int e=0;e<4;e++) r[e] = f2b(g0*b2f(a[e]) + g1*b2f(b[e]) + g2*b2f(cc[e]));
    *(short4v*)(comb + (size_t)i*HID + t*4) = r;
}

// ---------------------------------------------------------------------------
// out = comb (bf16 2048x1024) @ wb^T (bf16 1024x1024), f32 out.
// 64x64 tile, 512 blocks, double-buffered LDS, reg-staged prefetch.
__global__ __launch_bounds__(256) void k_gemm(
    const short* __restrict__ A, const short* __restrict__ Bw, float* __restrict__ out)
{
    __shared__ char ab[2][64*128];
    __shared__ char bb[2][64*128];
    int m0 = blockIdx.x*64, n0 = blockIdx.y*64, t = threadIdx.x;
    int w = t>>6, lane = t&63, c = lane&15, lg = lane>>4;
    int r0 = t>>3, ch0 = t&7;
    f32x4 acc[4];
    #pragma unroll
    for (int ct=0;ct<4;ct++) acc[ct] = (f32x4)0.f;
    const short* Ap = A  + (size_t)(m0+r0)*HID + ch0*8;
    const short* Bp = Bw + (size_t)(n0+r0)*HID + ch0*8;
    short8v ra0 = *(const short8v*)(Ap);
    short8v ra1 = *(const short8v*)(Ap + 32*HID);
    short8v rb0 = *(const short8v*)(Bp);
    short8v rb1 = *(const short8v*)(Bp + 32*HID);
    for (int kc=0;kc<16;kc++){
        char* abuf = ab[kc&1];
        char* bbuf = bb[kc&1];
        *(short8v*)(abuf + SWZ(r0*128 + ch0*16, r0)) = ra0;
        *(short8v*)(abuf + SWZ((r0+32)*128 + ch0*16, r0+32)) = ra1;
        *(short8v*)(bbuf + SWZ(r0*128 + ch0*16, r0)) = rb0;
        *(short8v*)(bbuf + SWZ((r0+32)*128 + ch0*16, r0+32)) = rb1;
        __syncthreads();
        if (kc < 15){
            const short* Ap2 = Ap + (kc+1)*64;
            const short* Bp2 = Bp + (kc+1)*64;
            ra0 = *(const short8v*)(Ap2);
            ra1 = *(const short8v*)(Ap2 + 32*HID);
            rb0 = *(const short8v*)(Bp2);
            rb1 = *(const short8v*)(Bp2 + 32*HID);
        }
        #pragma unroll
        for (int ks=0;ks<2;ks++){
            int arow = w*16 + c;
            short8v af = *(short8v*)(abuf + SWZ(arow*128 + ks*64 + lg*16, arow));
            #pragma unroll
            for (int ct=0;ct<4;ct++){
                int brow = ct*16 + c;
                short8v bf = *(short8v*)(bbuf + SWZ(brow*128 + ks*64 + lg*16, brow));
                acc[ct] = MFMA(af, bf, acc[ct]);
            }
        }
    }
    #pragma unroll
    for (int ct=0;ct<4;ct++)
        #pragma unroll
        for (int reg=0;reg<4;reg++){
            int row = w*16 + lg*4 + reg;
            out[((size_t)(m0+row))*HID + n0 + ct*16 + c] = acc[ct][reg];
        }
}

// ---------------------------------------------------------------------------
extern "C" void kernel_launch(void* const* d_in, const int* in_sizes, int n_in,
                              void* d_out, int out_size, void* d_ws, size_t ws_size,
                              hipStream_t stream)
{
    const float* hidden     = (const float*)d_in[0];
    const float* q          = (const float*)d_in[1];
    const float* k          = (const float*)d_in[2];
    const float* v          = (const float*)d_in[3];
    const float* memkv      = (const float*)d_in[4];
    const float* ksc        = (const float*)d_in[5];
    const float* vsc        = (const float*)d_in[6];
    const float* combiner_w = (const float*)d_in[7];
    const float* combiner_b = (const float*)d_in[8];
    const float* combine_w  = (const float*)d_in[9];
    float* out = (float*)d_out;

    char* p = (char*)d_ws;
    short* ckb  = (short*)p; p += (size_t)HKV*144*64*2;      // 73728
    short* cvtg = (short*)p; p += (size_t)HKV*64*160*2;      // 81920
    short* qbg  = (short*)p; p += (size_t)H*NN*D*2;          // 4 MB
    short* hbg  = (short*)p; p += (size_t)NN*HID*2;          // 4 MB
    short* wbg  = (short*)p; p += (size_t)HID*HID*2;         // 2 MB
    short* cwbg = (short*)p; p += (size_t)48*HID*2;          // 96 KB
    short* kbg  = (short*)p; p += (size_t)HKV*NN*D*2;        // 1 MB
    short* vTg  = (short*)p; p += (size_t)HKV*64*NN*2;       // 1 MB
    short* outc = (short*)p; p += (size_t)H*NN*D*2;          // 4 MB
    short* outf = (short*)p; p += (size_t)H*NN*D*2;          // 4 MB
    short* outs = (short*)p; p += (size_t)H*NN*D*2;          // 4 MB
    float* gpart= (float*)p; p += (size_t)4*NN*48*4;         // 1.5 MB
    short* comb = (short*)p; p += (size_t)NN*HID*2;          // 4 MB
    int*  selix = (int*)p;   p += (size_t)HKV*NN*NSEL*4;     // 512 KB

    hipFuncSetAttribute((const void*)k_cattn, hipFuncAttributeMaxDynamicSharedMemorySize, 125440);
    hipMemsetAsync(d_ws, 0, (size_t)HKV*144*64*2 + (size_t)HKV*64*160*2, stream);

    k_prep    <<<5937, 256, 0, stream>>>(q, hidden, combine_w, combiner_w, k, v,
                                          memkv, ksc, vsc,
                                          qbg, hbg, wbg, cwbg, kbg, vTg, ckb, cvtg);
    k_cattn   <<<dim3(NN/32, HKV), 256, 125440, stream>>>(qbg, ckb, cvtg, outc, selix);
    k_selattn <<<dim3(NN, HKV), 256, 0, stream>>>(q, k, v, selix, outf);
    k_swin    <<<dim3(NN/64, H), 256, 0, stream>>>(qbg, kbg, vTg, outs);
    k_gates   <<<dim3(NN/64, 4), 256, 0, stream>>>(hbg, cwbg, gpart);
    k_comb    <<<NN, 256, 0, stream>>>(outc, outf, outs, gpart, combiner_b, comb);
    k_gemm    <<<dim3(NN/64, HID/64), 256, 0, stream>>>(comb, wbg, out);
}

// Round 4
// 102.570 us; speedup vs baseline: 5.0132x; 1.0461x over previous
//
#include <hip/hip_runtime.h>
#include <hip/hip_bf16.h>
#include <math.h>

#define H    16
#define HKV  4
#define G    4
#define NN   2048
#define D    64
#define HID  1024
#define CB   16
#define W    128
#define NSEL 4
#define WIN  64
#define NEGV -1e10f
#define SCALE 0.125f

typedef __attribute__((ext_vector_type(4))) float f32x4;
typedef __attribute__((ext_vector_type(4))) short short4v;
typedef __attribute__((ext_vector_type(8))) short short8v;

__device__ inline short f2b(float x){
    __hip_bfloat16 h = __float2bfloat16(x);
    return *reinterpret_cast<short*>(&h);
}
__device__ inline float b2f(short s){
    unsigned u = ((unsigned)(unsigned short)s) << 16;
    return __builtin_bit_cast(float, u);
}
__device__ inline short8v cvt8(f32x4 a, f32x4 b){
    short8v r;
    r[0]=f2b(a[0]); r[1]=f2b(a[1]); r[2]=f2b(a[2]); r[3]=f2b(a[3]);
    r[4]=f2b(b[0]); r[5]=f2b(b[1]); r[6]=f2b(b[2]); r[7]=f2b(b[3]);
    return r;
}
#define SWZ(byte, row) ((byte) ^ (((row)&7)<<4))
#define MFMA(a,b,c) __builtin_amdgcn_mfma_f32_16x16x32_bf16(a,b,c,0,0,0)

__device__ inline float wave_sum(float x){ for(int o=32;o;o>>=1) x += __shfl_xor(x,o); return x; }
__device__ inline float wave_max(float x){ for(int o=32;o;o>>=1) x = fmaxf(x,__shfl_xor(x,o)); return x; }

__device__ inline f32x4 vmax4(f32x4 a, f32x4 b){
    f32x4 r; r[0]=fmaxf(a[0],b[0]); r[1]=fmaxf(a[1],b[1]); r[2]=fmaxf(a[2],b[2]); r[3]=fmaxf(a[3],b[3]); return r;
}
__device__ inline f32x4 shflx4(f32x4 x, int o){
    f32x4 r; r[0]=__shfl_xor(x[0],o); r[1]=__shfl_xor(x[1],o); r[2]=__shfl_xor(x[2],o); r[3]=__shfl_xor(x[3],o); return r;
}
__device__ inline f32x4 exp4(f32x4 x){
    f32x4 r; r[0]=expf(x[0]); r[1]=expf(x[1]); r[2]=expf(x[2]); r[3]=expf(x[3]); return r;
}

// ---------------------------------------------------------------------------
// fused prep: f32->bf16 converts (q, hidden, combine_w, combiner_w, k), V transpose,
// compressed K/V (incl. zero-fill of pad rows/cols). Block-range dispatch.
__device__ inline void conv_seg(const float* __restrict__ src, short* __restrict__ dst,
                                int b, int t){
    size_t idx = (size_t)b*1024 + t*4;
    f32x4 a = *(const f32x4*)(src + idx);
    short4v r; r[0]=f2b(a[0]); r[1]=f2b(a[1]); r[2]=f2b(a[2]); r[3]=f2b(a[3]);
    *(short4v*)(dst + idx) = r;
}

__global__ __launch_bounds__(256) void k_prep(
    const float* __restrict__ q, const float* __restrict__ hidden,
    const float* __restrict__ combine_w, const float* __restrict__ combiner_w,
    const float* __restrict__ k, const float* __restrict__ v,
    const float* __restrict__ memkv, const float* __restrict__ ksc, const float* __restrict__ vsc,
    short* __restrict__ qb, short* __restrict__ hb, short* __restrict__ wb,
    short* __restrict__ cwb, short* __restrict__ kb16, short* __restrict__ vT,
    short* __restrict__ ckb, short* __restrict__ cvtg)
{
    int b = blockIdx.x, t = threadIdx.x;
    if (b < 2048){ conv_seg(q, qb, b, t); return; }
    b -= 2048;
    if (b < 2048){ conv_seg(hidden, hb, b, t); return; }
    b -= 2048;
    if (b < 1024){ conv_seg(combine_w, wb, b, t); return; }
    b -= 1024;
    if (b < 48){ conv_seg(combiner_w, cwb, b, t); return; }
    b -= 48;
    if (b < 512){ conv_seg(k, kb16, b, t); return; }
    b -= 512;
    if (b < 128){
        // V transpose: vT[hk][d][i]
        __shared__ float tl[64][65];
        int hk = b>>5, i0 = (b&31)*64;
        for (int u=0;u<4;u++){
            int cid = t + 256*u; int r = cid>>4, ch = cid&15;
            f32x4 a = *(const f32x4*)(v + ((size_t)(hk*NN + i0 + r))*D + ch*4);
            tl[r][ch*4+0]=a[0]; tl[r][ch*4+1]=a[1]; tl[r][ch*4+2]=a[2]; tl[r][ch*4+3]=a[3];
        }
        __syncthreads();
        int d = t>>2, qd = t&3;
        short8v p0, p1;
        #pragma unroll
        for (int e=0;e<8;e++) p0[e] = f2b(tl[qd*16+e][d]);
        #pragma unroll
        for (int e=0;e<8;e++) p1[e] = f2b(tl[qd*16+8+e][d]);
        short* dst = vT + ((size_t)(hk*64 + d))*NN + i0 + qd*16;
        *(short8v*)dst = p0;
        *(short8v*)(dst+8) = p1;
        return;
    }
    b -= 128;
    {
        // compressed rows + pad zero-fill: j = b in 0..159, 4 waves = 4 hk
        int j = b;
        int hk = t>>6, d = t&63;
        if (j > 128){
            // pad: ckb rows 129..143 = 0, cvtg cols 129..159 = 0
            if (j < 144) ckb[((size_t)(hk*144 + j))*64 + d] = 0;
            cvtg[((size_t)(hk*64 + d))*160 + j] = 0;
            return;
        }
        float xk, xv;
        if (j==0){ xk = memkv[(0*HKV+hk)*D + d]; xv = memkv[(HKV+hk)*D + d]; }
        else {
            int jb = j-1;
            const float* kp = k + ((size_t)(hk*NN + jb*CB))*D + d;
            const float* vp = v + ((size_t)(hk*NN + jb*CB))*D + d;
            float sk=0.f, sv=0.f;
            #pragma unroll
            for (int tt=0;tt<CB;tt++){ sk += kp[tt*D]; sv += vp[tt*D]; }
            xk = sk*(1.0f/CB); xv = sv*(1.0f/CB);
            float msk = wave_sum(xk*xk)*(1.0f/D);
            float msv = wave_sum(xv*xv)*(1.0f/D);
            xk = xk*rsqrtf(msk+1e-6f)*ksc[d];
            xv = xv*rsqrtf(msv+1e-6f)*vsc[d];
        }
        ckb[((size_t)(hk*144 + j))*64 + d] = f2b(xk);
        cvtg[((size_t)(hk*64 + d))*160 + j] = f2b(xv);
    }
}

// ---------------------------------------------------------------------------
// compressed attention + importance + top-k. Block = (hk, 32 tokens), 4 waves.
__global__ __launch_bounds__(256) void k_cattn(
    const short* __restrict__ qb, const short* __restrict__ ckb, const short* __restrict__ cvt_g,
    short* __restrict__ outc, int* __restrict__ selidx)
{
    extern __shared__ char smem[];
    char* aq  = smem;                      // 128 * 128
    char* ckl = smem + 16384;              // 144 * 128
    char* cvl = smem + 34816;              // 64 * 384
    char* pl  = smem + 59392;              // 128 * 384
    float* impl = (float*)(smem + 108544); // 32*128 f32
    float* psl  = (float*)(smem + 124928); // 128 f32
    int i0 = blockIdx.x*32, hk = blockIdx.y, t = threadIdx.x;

    for (int u=0;u<4;u++){
        int cid = t + 256*u; int row = cid>>3, ch = cid&7;
        const short* src = qb + ((size_t)((hk*G + (row&3))*NN + i0 + (row>>2)))*D + ch*8;
        *(short8v*)(aq + SWZ(row*128 + ch*16, row)) = *(const short8v*)src;
    }
    for (int u=0;u<5;u++){
        int cid = t + 256*u;
        if (cid < 1152){
            int row = cid>>3, ch = cid&7;
            const short* src = ckb + ((size_t)(hk*144 + row))*64 + ch*8;
            *(short8v*)(ckl + SWZ(row*128 + ch*16, row)) = *(const short8v*)src;
        }
    }
    {
        int row = t>>2;
        for (int u=0;u<6;u++){
            int ch = (t&3) + 4*u;
            short8v val = (short8v)0;
            if (ch < 20) val = *(const short8v*)(cvt_g + ((size_t)(hk*64 + row))*160 + ch*8);
            *(short8v*)(cvl + SWZ(row*384 + ch*16, row)) = val;
        }
    }
    {
        int row = t>>1;
        for (int u=0;u<3;u++){
            int sl = (t&1)*3 + u;
            *(short8v*)(pl + SWZ(row*384 + 288 + sl*16, row)) = (short8v)0;
        }
    }
    __syncthreads();

    int w = t>>6, lane = t&63, c = lane&15, lg = lane>>4;
    f32x4 acc[2][9];
    #pragma unroll
    for (int r=0;r<2;r++)
        #pragma unroll
        for (int ct=0;ct<9;ct++) acc[r][ct] = (f32x4)0.f;

    #pragma unroll
    for (int ks=0;ks<2;ks++){
        short8v af[2];
        #pragma unroll
        for (int r=0;r<2;r++){
            int row = (w*2+r)*16 + c;
            af[r] = *(short8v*)(aq + SWZ(row*128 + ks*64 + lg*16, row));
        }
        #pragma unroll
        for (int ct=0;ct<9;ct++){
            int row = ct*16 + c;
            short8v bf = *(short8v*)(ckl + SWZ(row*128 + ks*64 + lg*16, row));
            #pragma unroll
            for (int r=0;r<2;r++) acc[r][ct] = MFMA(af[r], bf, acc[r][ct]);
        }
    }

    #pragma unroll
    for (int r=0;r<2;r++){
        int tloc = (w*2+r)*4 + lg;
        int ii = i0 + tloc;
        #pragma unroll
        for (int ct=0;ct<9;ct++){
            int j = ct*16 + c;
            bool vis = (j==0) || (j<=128 && j*16 <= ii);
            f32x4 s = acc[r][ct]*SCALE;
            if (!vis){ s[0]=NEGV; s[1]=NEGV; s[2]=NEGV; s[3]=NEGV; }
            acc[r][ct] = s;
        }
        #pragma unroll
        for (int ct=0;ct<9;ct++){
            int j = ct*16 + c;
            if (j>=1 && j<=128){
                f32x4 s = acc[r][ct];
                impl[tloc*128 + (j-1)] = 0.25f*(s[0]+s[1]+s[2]+s[3]);
            }
        }
        f32x4 mx = acc[r][0];
        #pragma unroll
        for (int ct=1;ct<9;ct++) mx = vmax4(mx, acc[r][ct]);
        #pragma unroll
        for (int o=1;o<16;o<<=1) mx = vmax4(mx, shflx4(mx,o));
        f32x4 sum = (f32x4)0.f;
        #pragma unroll
        for (int ct=0;ct<9;ct++){ acc[r][ct] = exp4(acc[r][ct]-mx); sum += acc[r][ct]; }
        #pragma unroll
        for (int o=1;o<16;o<<=1) sum += shflx4(sum,o);
        #pragma unroll
        for (int ct=0;ct<9;ct++){
            #pragma unroll
            for (int reg=0;reg<4;reg++){
                int row = (w*2+r)*16 + lg*4 + reg;
                *(short*)(pl + SWZ(row*384 + (ct*16+c)*2, row)) = f2b(acc[r][ct][reg]);
            }
        }
        if (c==0){
            #pragma unroll
            for (int reg=0;reg<4;reg++) psl[(w*2+r)*16 + lg*4 + reg] = sum[reg];
        }
    }
    __syncthreads();

    #pragma unroll 1
    for (int s8=0;s8<8;s8++){
        int tt = w*8 + s8;
        float v0 = impl[tt*128 + lane];
        float v1 = impl[tt*128 + 64 + lane];
        int sel[4];
        #pragma unroll
        for (int r4=0;r4<4;r4++){
            float bv; int bj;
            if (v1 > v0){ bv=v1; bj=lane+64; } else { bv=v0; bj=lane; }
            #pragma unroll
            for (int o=32;o;o>>=1){
                float ov = __shfl_xor(bv,o);
                int oj = __shfl_xor(bj,o);
                if (ov > bv || (ov==bv && oj<bj)){ bv=ov; bj=oj; }
            }
            sel[r4]=bj;
            if (bj==lane) v0 = -INFINITY;
            else if (bj==lane+64) v1 = -INFINITY;
        }
        if (lane==0){
            int* sp = selidx + ((size_t)(hk*NN + i0 + tt))*NSEL;
            sp[0]=sel[0]; sp[1]=sel[1]; sp[2]=sel[2]; sp[3]=sel[3];
        }
    }

    f32x4 pv[2][4];
    #pragma unroll
    for (int r=0;r<2;r++)
        #pragma unroll
        for (int ctd=0;ctd<4;ctd++) pv[r][ctd] = (f32x4)0.f;
    #pragma unroll
    for (int ks=0;ks<5;ks++){
        short8v pf[2];
        #pragma unroll
        for (int r=0;r<2;r++){
            int row = (w*2+r)*16 + c;
            pf[r] = *(short8v*)(pl + SWZ(row*384 + ks*64 + lg*16, row));
        }
        #pragma unroll
        for (int ctd=0;ctd<4;ctd++){
            int row = ctd*16 + c;
            short8v bf = *(short8v*)(cvl + SWZ(row*384 + ks*64 + lg*16, row));
            #pragma unroll
            for (int r=0;r<2;r++) pv[r][ctd] = MFMA(pf[r], bf, pv[r][ctd]);
        }
    }
    #pragma unroll
    for (int r=0;r<2;r++)
        #pragma unroll
        for (int ctd=0;ctd<4;ctd++)
            #pragma unroll
            for (int reg=0;reg<4;reg++){
                int row = (w*2+r)*16 + lg*4 + reg;
                float inv = 1.0f/psl[row];
                int hh = hk*G + reg;
                int ii = i0 + (row>>2);
                outc[((size_t)(hh*NN + ii))*D + ctd*16 + c] = f2b(pv[r][ctd][reg]*inv);
            }
}

// ---------------------------------------------------------------------------
// selected-block attention, fp32. Block = (i, hk); 4 waves = 4 heads.
__global__ __launch_bounds__(256) void k_selattn(
    const float* __restrict__ q, const float* __restrict__ k, const float* __restrict__ v,
    const int* __restrict__ selidx, short* __restrict__ outf)
{
    __shared__ char ksl[64*256];
    __shared__ float vs[64*64];
    __shared__ float qs[256];
    __shared__ float ps[256];
    __shared__ int sel_s[4];
    int i = blockIdx.x, hk = blockIdx.y, t = threadIdx.x;
    if (t < 4) sel_s[t] = selidx[((size_t)(hk*NN + i))*NSEL + t];
    __syncthreads();
    {
        int hh = t>>6, d = t&63;
        qs[t] = q[((size_t)((hk*G+hh)*NN + i))*D + d];
    }
    for (int u=0;u<4;u++){
        int cid = t + 256*u; int row = cid>>4, ch = cid&15;
        int pos = sel_s[row>>4]*CB + (row&15);
        f32x4 kk = *(const f32x4*)(k + ((size_t)(hk*NN + pos))*D + ch*4);
        *(f32x4*)(ksl + SWZ(row*256 + ch*16, row)) = kk;
        f32x4 vv = *(const f32x4*)(v + ((size_t)(hk*NN + pos))*D + ch*4);
        *(f32x4*)((char*)vs + row*256 + ch*16) = vv;
    }
    __syncthreads();
    int wv = t>>6, lane = t&63;
    f32x4 qr[16];
    #pragma unroll
    for (int d4=0;d4<16;d4++) qr[d4] = *(f32x4*)(qs + wv*64 + d4*4);
    int pos_l = sel_s[lane>>4]*CB + (lane&15);
    float s = 0.f;
    #pragma unroll
    for (int d4=0;d4<16;d4++){
        f32x4 kk = *(f32x4*)(ksl + SWZ(lane*256 + d4*16, lane));
        s += qr[d4][0]*kk[0] + qr[d4][1]*kk[1] + qr[d4][2]*kk[2] + qr[d4][3]*kk[3];
    }
    s *= SCALE;
    if (pos_l > i) s = NEGV;
    float m = wave_max(s);
    float p = expf(s - m);
    float psum = wave_sum(p);
    ps[wv*64 + lane] = p;
    __syncthreads();
    int jg = lane>>4, dg = lane&15;
    f32x4 partial = (f32x4)0.f;
    #pragma unroll
    for (int jj=0;jj<16;jj++){
        int j = jg*16 + jj;
        float pw = ps[wv*64 + j];
        f32x4 vv = *(f32x4*)(vs + j*64 + dg*4);
        partial += vv * pw;
    }
    partial += shflx4(partial, 16);
    partial += shflx4(partial, 32);
    if (lane < 16){
        float inv = 1.0f/psum;
        short4v r;
        r[0]=f2b(partial[0]*inv); r[1]=f2b(partial[1]*inv);
        r[2]=f2b(partial[2]*inv); r[3]=f2b(partial[3]*inv);
        *(short4v*)(outf + ((size_t)((hk*G+wv)*NN + i))*D + dg*4) = r;
    }
}

// ---------------------------------------------------------------------------
// sliding-window attention, bf16 MFMA. Block = (h, 64 tokens); keys pa..pa+127.
__global__ __launch_bounds__(256) void k_swin(
    const short* __restrict__ qb, const short* __restrict__ kb16, const short* __restrict__ vT,
    short* __restrict__ outs)
{
    __shared__ char aq[64*128];
    __shared__ char kb[128*128];
    __shared__ char vl[64*256];
    __shared__ char pl[64*256];
    __shared__ float psl[64];
    int i0 = blockIdx.x*64, h = blockIdx.y, t = threadIdx.x;
    int hk = h >> 2;
    int pa = i0 - 64;
    for (int u=0;u<2;u++){
        int cid = t + 256*u; int row = cid>>3, ch = cid&7;
        *(short8v*)(aq + SWZ(row*128 + ch*16, row)) =
            *(const short8v*)(qb + ((size_t)(h*NN + i0 + row))*D + ch*8);
    }
    for (int u=0;u<4;u++){
        int cid = t + 256*u; int row = cid>>3, ch = cid&7;
        int pos = pa + row; pos = pos < 0 ? 0 : pos;
        *(short8v*)(kb + SWZ(row*128 + ch*16, row)) =
            *(const short8v*)(kb16 + ((size_t)(hk*NN + pos))*D + ch*8);
    }
    for (int u=0;u<4;u++){
        int cid = t + 256*u; int d = cid>>4, ch = cid&15;
        int ps0 = pa + ch*8;
        short8v val;
        const short* src = vT + ((size_t)(hk*64 + d))*NN + ps0;
        if (ps0 >= 0) val = *(const short8v*)src;
        else {
            #pragma unroll
            for (int e=0;e<8;e++){ int pp = ps0+e; pp = pp<0?0:pp; val[e] = vT[((size_t)(hk*64+d))*NN + pp]; }
        }
        *(short8v*)(vl + SWZ(d*256 + ch*16, d)) = val;
    }
    __syncthreads();
    int w = t>>6, lane = t&63, c = lane&15, lg = lane>>4;
    f32x4 acc[8];
    #pragma unroll
    for (int ct=0;ct<8;ct++) acc[ct] = (f32x4)0.f;
    #pragma unroll
    for (int ks=0;ks<2;ks++){
        int arow = w*16 + c;
        short8v af = *(short8v*)(aq + SWZ(arow*128 + ks*64 + lg*16, arow));
        #pragma unroll
        for (int ct=0;ct<8;ct++){
            int brow = ct*16 + c;
            short8v bf = *(short8v*)(kb + SWZ(brow*128 + ks*64 + lg*16, brow));
            acc[ct] = MFMA(af, bf, acc[ct]);
        }
    }
    #pragma unroll
    for (int ct=0;ct<8;ct++){
        int j = ct*16 + c;
        #pragma unroll
        for (int reg=0;reg<4;reg++){
            int tl = w*16 + lg*4 + reg;
            bool vis = (j >= tl+1) && (j <= tl+64) && (pa + j >= 0);
            float s = acc[ct][reg]*SCALE;
            acc[ct][reg] = vis ? s : NEGV;
        }
    }
    f32x4 mx = acc[0];
    #pragma unroll
    for (int ct=1;ct<8;ct++) mx = vmax4(mx, acc[ct]);
    #pragma unroll
    for (int o=1;o<16;o<<=1) mx = vmax4(mx, shflx4(mx,o));
    f32x4 sum = (f32x4)0.f;
    #pragma unroll
    for (int ct=0;ct<8;ct++){ acc[ct] = exp4(acc[ct]-mx); sum += acc[ct]; }
    #pragma unroll
    for (int o=1;o<16;o<<=1) sum += shflx4(sum,o);
    #pragma unroll
    for (int ct=0;ct<8;ct++){
        #pragma unroll
        for (int reg=0;reg<4;reg++){
            int row = w*16 + lg*4 + reg;
            *(short*)(pl + SWZ(row*256 + (ct*16+c)*2, row)) = f2b(acc[ct][reg]);
        }
    }
    if (c==0){
        #pragma unroll
        for (int reg=0;reg<4;reg++) psl[w*16+lg*4+reg] = sum[reg];
    }
    __syncthreads();
    f32x4 pv[4];
    #pragma unroll
    for (int ctd=0;ctd<4;ctd++) pv[ctd] = (f32x4)0.f;
    #pragma unroll
    for (int ks=0;ks<4;ks++){
        int arow = w*16 + c;
        short8v pf = *(short8v*)(pl + SWZ(arow*256 + ks*64 + lg*16, arow));
        #pragma unroll
        for (int ctd=0;ctd<4;ctd++){
            int brow = ctd*16 + c;
            short8v bf = *(short8v*)(vl + SWZ(brow*256 + ks*64 + lg*16, brow));
            pv[ctd] = MFMA(pf, bf, pv[ctd]);
        }
    }
    #pragma unroll
    for (int ctd=0;ctd<4;ctd++)
        #pragma unroll
        for (int reg=0;reg<4;reg++){
            int row = w*16 + lg*4 + reg;
            float inv = 1.0f/psl[row];
            outs[((size_t)(h*NN + i0 + row))*D + ctd*16 + c] = f2b(pv[ctd][reg]*inv);
        }
}

// ---------------------------------------------------------------------------
// gates split-K partial GEMM: gpart[ky][token][48] = hb(64 tok) @ cwb^T over K-chunk ky.
__global__ __launch_bounds__(256) void k_gates(
    const short* __restrict__ hb, const short* __restrict__ cwb, float* __restrict__ gpart)
{
    __shared__ char ha[64*128];
    __shared__ char bl[48*128];
    int i0 = blockIdx.x*64, ky = blockIdx.y, t = threadIdx.x;
    int w = t>>6, lane = t&63, c = lane&15, lg = lane>>4;
    f32x4 acc[3];
    #pragma unroll
    for (int ct=0;ct<3;ct++) acc[ct] = (f32x4)0.f;
    for (int kc=0;kc<4;kc++){
        int kbase = ky*256 + kc*64;
        if (kc) __syncthreads();
        for (int u=0;u<2;u++){
            int cid = t + 256*u; int row = cid>>3, ch = cid&7;
            *(short8v*)(ha + SWZ(row*128 + ch*16, row)) =
                *(const short8v*)(hb + (size_t)(i0+row)*HID + kbase + ch*8);
        }
        for (int u=0;u<2;u++){
            int cid = t + 256*u;
            if (cid < 384){
                int row = cid>>3, ch = cid&7;
                *(short8v*)(bl + SWZ(row*128 + ch*16, row)) =
                    *(const short8v*)(cwb + (size_t)row*HID + kbase + ch*8);
            }
        }
        __syncthreads();
        #pragma unroll
        for (int ks=0;ks<2;ks++){
            int arow = w*16 + c;
            short8v af = *(short8v*)(ha + SWZ(arow*128 + ks*64 + lg*16, arow));
            #pragma unroll
            for (int ct=0;ct<3;ct++){
                int brow = ct*16 + c;
                short8v bf = *(short8v*)(bl + SWZ(brow*128 + ks*64 + lg*16, brow));
                acc[ct] = MFMA(af, bf, acc[ct]);
            }
        }
    }
    #pragma unroll
    for (int ct=0;ct<3;ct++)
        #pragma unroll
        for (int reg=0;reg<4;reg++){
            int row = w*16 + lg*4 + reg;
            gpart[((size_t)ky*NN + i0 + row)*48 + ct*16 + c] = acc[ct][reg];
        }
}

// ---------------------------------------------------------------------------
// gated combine (sums gate partials + bias + sigmoid in-block) -> comb bf16 [N][HID]
__global__ __launch_bounds__(256) void k_comb(
    const short* __restrict__ outc, const short* __restrict__ outf, const short* __restrict__ outs_,
    const float* __restrict__ gpart, const float* __restrict__ cb, short* __restrict__ comb)
{
    __shared__ float gs[48];
    int i = blockIdx.x, t = threadIdx.x;
    if (t < 48){
        float s = gpart[(size_t)0*NN*48 + i*48 + t] + gpart[(size_t)1*NN*48 + i*48 + t]
                + gpart[(size_t)2*NN*48 + i*48 + t] + gpart[(size_t)3*NN*48 + i*48 + t] + cb[t];
        gs[t] = 1.0f/(1.0f+expf(-s));
    }
    __syncthreads();
    int hh = t>>4, d0 = (t&15)*4;
    float g0 = gs[hh*3], g1 = gs[hh*3+1], g2 = gs[hh*3+2];
    size_t off = ((size_t)(hh*NN + i))*D + d0;
    short4v a = *(const short4v*)(outc + off);
    short4v b = *(const short4v*)(outf + off);
    short4v cc = *(const short4v*)(outs_ + off);
    short4v r;
    #pragma unroll
    for (int e=0;e<4;e++) r[e] = f2b(g0*b2f(a[e]) + g1*b2f(b[e]) + g2*b2f(cc[e]));
    *(short4v*)(comb + (size_t)i*HID + t*4) = r;
}

// ---------------------------------------------------------------------------
// out = comb (bf16 2048x1024) @ wb^T (bf16 1024x1024), f32 out.
// 64x64 tile, 512 blocks, double-buffered LDS, reg-staged prefetch.
__global__ __launch_bounds__(256) void k_gemm(
    const short* __restrict__ A, const short* __restrict__ Bw, float* __restrict__ out)
{
    __shared__ char ab[2][64*128];
    __shared__ char bb[2][64*128];
    int m0 = blockIdx.x*64, n0 = blockIdx.y*64, t = threadIdx.x;
    int w = t>>6, lane = t&63, c = lane&15, lg = lane>>4;
    int r0 = t>>3, ch0 = t&7;
    f32x4 acc[4];
    #pragma unroll
    for (int ct=0;ct<4;ct++) acc[ct] = (f32x4)0.f;
    const short* Ap = A  + (size_t)(m0+r0)*HID + ch0*8;
    const short* Bp = Bw + (size_t)(n0+r0)*HID + ch0*8;
    short8v ra0 = *(const short8v*)(Ap);
    short8v ra1 = *(const short8v*)(Ap + 32*HID);
    short8v rb0 = *(const short8v*)(Bp);
    short8v rb1 = *(const short8v*)(Bp + 32*HID);
    for (int kc=0;kc<16;kc++){
        char* abuf = ab[kc&1];
        char* bbuf = bb[kc&1];
        *(short8v*)(abuf + SWZ(r0*128 + ch0*16, r0)) = ra0;
        *(short8v*)(abuf + SWZ((r0+32)*128 + ch0*16, r0+32)) = ra1;
        *(short8v*)(bbuf + SWZ(r0*128 + ch0*16, r0)) = rb0;
        *(short8v*)(bbuf + SWZ((r0+32)*128 + ch0*16, r0+32)) = rb1;
        __syncthreads();
        if (kc < 15){
            const short* Ap2 = Ap + (kc+1)*64;
            const short* Bp2 = Bp + (kc+1)*64;
            ra0 = *(const short8v*)(Ap2);
            ra1 = *(const short8v*)(Ap2 + 32*HID);
            rb0 = *(const short8v*)(Bp2);
            rb1 = *(const short8v*)(Bp2 + 32*HID);
        }
        #pragma unroll
        for (int ks=0;ks<2;ks++){
            int arow = w*16 + c;
            short8v af = *(short8v*)(abuf + SWZ(arow*128 + ks*64 + lg*16, arow));
            #pragma unroll
            for (int ct=0;ct<4;ct++){
                int brow = ct*16 + c;
                short8v bf = *(short8v*)(bbuf + SWZ(brow*128 + ks*64 + lg*16, brow));
                acc[ct] = MFMA(af, bf, acc[ct]);
            }
        }
    }
    #pragma unroll
    for (int ct=0;ct<4;ct++)
        #pragma unroll
        for (int reg=0;reg<4;reg++){
            int row = w*16 + lg*4 + reg;
            out[((size_t)(m0+row))*HID + n0 + ct*16 + c] = acc[ct][reg];
        }
}

// ---------------------------------------------------------------------------
extern "C" void kernel_launch(void* const* d_in, const int* in_sizes, int n_in,
                              void* d_out, int out_size, void* d_ws, size_t ws_size,
                              hipStream_t stream)
{
    const float* hidden     = (const float*)d_in[0];
    const float* q          = (const float*)d_in[1];
    const float* k          = (const float*)d_in[2];
    const float* v          = (const float*)d_in[3];
    const float* memkv      = (const float*)d_in[4];
    const float* ksc        = (const float*)d_in[5];
    const float* vsc        = (const float*)d_in[6];
    const float* combiner_w = (const float*)d_in[7];
    const float* combiner_b = (const float*)d_in[8];
    const float* combine_w  = (const float*)d_in[9];
    float* out = (float*)d_out;

    char* p = (char*)d_ws;
    short* ckb  = (short*)p; p += (size_t)HKV*144*64*2;      // 73728
    short* cvtg = (short*)p; p += (size_t)HKV*64*160*2;      // 81920
    short* qbg  = (short*)p; p += (size_t)H*NN*D*2;          // 4 MB
    short* hbg  = (short*)p; p += (size_t)NN*HID*2;          // 4 MB
    short* wbg  = (short*)p; p += (size_t)HID*HID*2;         // 2 MB
    short* cwbg = (short*)p; p += (size_t)48*HID*2;          // 96 KB
    short* kbg  = (short*)p; p += (size_t)HKV*NN*D*2;        // 1 MB
    short* vTg  = (short*)p; p += (size_t)HKV*64*NN*2;       // 1 MB
    short* outc = (short*)p; p += (size_t)H*NN*D*2;          // 4 MB
    short* outf = (short*)p; p += (size_t)H*NN*D*2;          // 4 MB
    short* outs = (short*)p; p += (size_t)H*NN*D*2;          // 4 MB
    float* gpart= (float*)p; p += (size_t)4*NN*48*4;         // 1.5 MB
    short* comb = (short*)p; p += (size_t)NN*HID*2;          // 4 MB
    int*  selix = (int*)p;   p += (size_t)HKV*NN*NSEL*4;     // 512 KB

    hipFuncSetAttribute((const void*)k_cattn, hipFuncAttributeMaxDynamicSharedMemorySize, 125440);

    k_prep    <<<5968, 256, 0, stream>>>(q, hidden, combine_w, combiner_w, k, v,
                                          memkv, ksc, vsc,
                                          qbg, hbg, wbg, cwbg, kbg, vTg, ckb, cvtg);
    k_cattn   <<<dim3(NN/32, HKV), 256, 125440, stream>>>(qbg, ckb, cvtg, outc, selix);
    k_selattn <<<dim3(NN, HKV), 256, 0, stream>>>(q, k, v, selix, outf);
    k_swin    <<<dim3(NN/64, H), 256, 0, stream>>>(qbg, kbg, vTg, outs);
    k_gates   <<<dim3(NN/64, 4), 256, 0, stream>>>(hbg, cwbg, gpart);
    k_comb    <<<NN, 256, 0, stream>>>(outc, outf, outs, gpart, combiner_b, comb);
    k_gemm    <<<dim3(NN/64, HID/64), 256, 0, stream>>>(comb, wbg, out);
}